// Round 4
// baseline (583.965 us; speedup 1.0000x reference)
//
#include <hip/hip_runtime.h>

#define Gn 4
#define Nn 50000
#define En 800000
#define Bq 32
#define F_IN 64
#define Hn 128
#define NNODES 50000
#define NBK 196     // dest buckets per graph (dest >> 8), 256 nodes each
#define EB 98       // edge chunks per graph (8192 edges each)

using v8s = __attribute__((ext_vector_type(8))) short;
using v4f = __attribute__((ext_vector_type(4))) float;

// ---- bf16 helpers (RNE) ----
__device__ __forceinline__ float bf2f(unsigned short u) {
    unsigned int x = ((unsigned int)u) << 16;
    float f; __builtin_memcpy(&f, &x, 4); return f;
}
__device__ __forceinline__ unsigned short f2bf(float f) {
    unsigned int x; __builtin_memcpy(&x, &f, 4);
    x = (x + 0x7fffu + ((x >> 16) & 1u)) >> 16;
    return (unsigned short)x;
}

// ---------------- phase 1: coarse bucket totals (bucket = dest>>8) ----------------
__global__ __launch_bounds__(256) void k_btot(const int* __restrict__ ei, int* __restrict__ btot) {
    __shared__ int h[NBK];
    int g = blockIdx.y;
    const int* col = ei + (size_t)g * 2 * En + En;
    for (int i = threadIdx.x; i < NBK; i += 256) h[i] = 0;
    __syncthreads();
    int e0 = blockIdx.x * 8192, e1 = min(e0 + 8192, En);
    for (int i = e0 / 4 + threadIdx.x; i < e1 / 4; i += 256) {
        int4 c = ((const int4*)col)[i];
        atomicAdd(&h[c.x >> 8], 1);
        atomicAdd(&h[c.y >> 8], 1);
        atomicAdd(&h[c.z >> 8], 1);
        atomicAdd(&h[c.w >> 8], 1);
    }
    __syncthreads();
    for (int i = threadIdx.x; i < NBK; i += 256)
        if (h[i]) atomicAdd(&btot[g * NBK + i], h[i]);
}

// ---------------- phase 2: scan bucket totals -> bases + global cursors ----------------
__global__ __launch_bounds__(256) void k_bbase(const int* __restrict__ btot, int* __restrict__ bbase,
                                               int* __restrict__ bcur) {
    __shared__ int s[256];
    int g = blockIdx.x, t = threadIdx.x;
    int v = (t < NBK) ? btot[g * NBK + t] : 0;
    s[t] = v;
    __syncthreads();
    for (int d = 1; d < 256; d <<= 1) {
        int u = (t >= d) ? s[t - d] : 0;
        __syncthreads();
        s[t] += u;
        __syncthreads();
    }
    if (t < NBK) { int b = s[t] - v; bbase[g * NBK + t] = b; bcur[g * NBK + t] = b; }
}

// ---------------- phase 3: bucketize edges into packed pairs (r<<16|c) ----------------
__global__ __launch_bounds__(256) void k_bucket(const int* __restrict__ ei, int* __restrict__ bcur,
                                                unsigned int* __restrict__ pairs) {
    __shared__ int h[NBK];
    __shared__ int gbase[NBK];
    int g = blockIdx.y;
    const int* row = ei + (size_t)g * 2 * En;
    const int* col = row + En;
    unsigned int* pg = pairs + (size_t)g * En;
    for (int i = threadIdx.x; i < NBK; i += 256) h[i] = 0;
    __syncthreads();
    int e0 = blockIdx.x * 8192, e1 = min(e0 + 8192, En);
    for (int i = e0 / 4 + threadIdx.x; i < e1 / 4; i += 256) {
        int4 c = ((const int4*)col)[i];
        atomicAdd(&h[c.x >> 8], 1);
        atomicAdd(&h[c.y >> 8], 1);
        atomicAdd(&h[c.z >> 8], 1);
        atomicAdd(&h[c.w >> 8], 1);
    }
    __syncthreads();
    for (int i = threadIdx.x; i < NBK; i += 256) {
        int cnt = h[i];
        gbase[i] = cnt ? atomicAdd(&bcur[g * NBK + i], cnt) : 0;
        h[i] = 0;  // becomes local cursor
    }
    __syncthreads();
    for (int i = e0 / 4 + threadIdx.x; i < e1 / 4; i += 256) {
        int4 c = ((const int4*)col)[i];
        int4 r = ((const int4*)row)[i];
        int p;
        p = gbase[c.x >> 8] + atomicAdd(&h[c.x >> 8], 1); pg[p] = ((unsigned)r.x << 16) | (unsigned)c.x;
        p = gbase[c.y >> 8] + atomicAdd(&h[c.y >> 8], 1); pg[p] = ((unsigned)r.y << 16) | (unsigned)c.y;
        p = gbase[c.z >> 8] + atomicAdd(&h[c.z >> 8], 1); pg[p] = ((unsigned)r.z << 16) | (unsigned)c.z;
        p = gbase[c.w >> 8] + atomicAdd(&h[c.w >> 8], 1); pg[p] = ((unsigned)r.w << 16) | (unsigned)c.w;
    }
}

// ---------------- phase 4 (fused): per-bucket count + scan -> off/dinv, then LDS-cursor fill ----------------
__global__ __launch_bounds__(256) void k_fillb2(const unsigned int* __restrict__ pairs,
                                                const int* __restrict__ bbase, const int* __restrict__ btot,
                                                int* __restrict__ off, float* __restrict__ dinv,
                                                unsigned short* __restrict__ srcs) {
    __shared__ int h[256], sc[256], curL[256];
    int g = blockIdx.y, b = blockIdx.x, t = threadIdx.x;
    int beg = bbase[g * NBK + b], cnt = btot[g * NBK + b];
    const unsigned int* pg = pairs + (size_t)g * En + beg;
    unsigned short* sg = srcs + (size_t)g * En;
    h[t] = 0;
    __syncthreads();
    for (int i = t; i < cnt; i += 256) atomicAdd(&h[pg[i] & 255], 1);
    __syncthreads();
    int d = h[t];
    sc[t] = d;
    __syncthreads();
    for (int dd = 1; dd < 256; dd <<= 1) {
        int u = (t >= dd) ? sc[t - dd] : 0;
        __syncthreads();
        sc[t] += u;
        __syncthreads();
    }
    int myoff = beg + sc[t] - d;  // exclusive
    int node = b * 256 + t;
    if (node < Nn) {
        off[g * (Nn + 1) + node] = myoff;
        dinv[g * Nn + node] = rsqrtf((float)d + 1.0f);
    }
    if (b == NBK - 1 && t == 255) off[g * (Nn + 1) + Nn] = beg + sc[255];
    curL[t] = myoff;
    __syncthreads();
    for (int i = t; i < cnt; i += 256) {
        unsigned int pr = pg[i];
        int pos = atomicAdd(&curL[pr & 255], 1);
        sg[pos] = (unsigned short)(pr >> 16);
    }
}

// ---------------- cast + pre-scale: xbs = bf16(x * dinv), all graphs ----------------
__global__ __launch_bounds__(256) void k_cast(const float* __restrict__ x, const float* __restrict__ dinv,
                                              unsigned short* __restrict__ xbs) {
    int g = blockIdx.y;
    int i = blockIdx.x * 256 + threadIdx.x;  // float4 index within graph
    if (i >= Nn * 16) return;
    float dc = dinv[g * Nn + (i >> 4)];
    float4 v = *(const float4*)&x[(size_t)g * Nn * 64 + i * 4];
    ushort4 u = make_ushort4(f2bf(v.x * dc), f2bf(v.y * dc), f2bf(v.z * dc), f2bf(v.w * dc));
    *(ushort4*)&xbs[(size_t)g * Nn * 64 + i * 4] = u;
}

// ---------------- agg 64-feat, feature-split (z = half): footprint 3.2MB/graph/pass ----------------
__global__ __launch_bounds__(256) void k_agg1(const unsigned short* __restrict__ xs_, const int* __restrict__ off_,
                                              const unsigned short* __restrict__ srcs_,
                                              const float* __restrict__ dinv_, unsigned short* __restrict__ z1_) {
    int g = blockIdx.y;
    int fb = blockIdx.z * 32;  // feature base (shorts) for this half
    const unsigned short* xs = xs_ + (size_t)g * Nn * 64;
    const int* off = off_ + g * (Nn + 1);
    const unsigned short* srcs = srcs_ + (size_t)g * En;
    unsigned short* z1 = z1_ + (size_t)g * Nn * 64;
    int node = blockIdx.x * 8 + (threadIdx.x >> 5);
    int lane = threadIdx.x & 31;
    int sub = lane >> 3;   // edge slot 0..3
    int fo = lane & 7;     // feature quad: feats fb + [fo*4, fo*4+4)
    int beg = off[node], end = off[node + 1];
    float acc[4] = {};
    for (int e = beg; e < end; e += 32) {
        int rem = end - e;
        // 8 independent edge-id loads per lane (broadcast across the 8 fo-lanes).
        // May pre-read up to 60 B past this graph's srcs slice; lands in zeroed
        // emb region of our workspace and is guarded before use.
        int sj[8];
#pragma unroll
        for (int jj = 0; jj < 8; ++jj) sj[jj] = srcs[e + jj * 4 + sub];
#pragma unroll
        for (int jj = 0; jj < 8; ++jj) {
            if (jj * 4 + sub < rem) {
                ushort4 u = *(const ushort4*)&xs[(long)sj[jj] * 64 + fb + fo * 4];
                acc[0] += bf2f(u.x);
                acc[1] += bf2f(u.y);
                acc[2] += bf2f(u.z);
                acc[3] += bf2f(u.w);
            }
        }
    }
#pragma unroll
    for (int q = 0; q < 4; ++q) {
        acc[q] += __shfl_xor(acc[q], 8, 32);
        acc[q] += __shfl_xor(acc[q], 16, 32);
    }
    if (sub == 0) {
        float dc = dinv_[g * Nn + node];
        ushort4 ow = *(const ushort4*)&xs[(long)node * 64 + fb + fo * 4];
        ushort4 o;
        o.x = f2bf((acc[0] + bf2f(ow.x)) * dc);
        o.y = f2bf((acc[1] + bf2f(ow.y)) * dc);
        o.z = f2bf((acc[2] + bf2f(ow.z)) * dc);
        o.w = f2bf((acc[3] + bf2f(ow.w)) * dc);
        *(ushort4*)&z1[(long)node * 64 + fb + fo * 4] = o;
    }
}

// ---------------- agg 128-feat, feature-split (z = half): footprint 6.4MB/graph/pass ----------------
__global__ __launch_bounds__(256) void k_agg2(const unsigned short* __restrict__ h_, const int* __restrict__ off_,
                                              const unsigned short* __restrict__ srcs_,
                                              const float* __restrict__ dinv_, unsigned short* __restrict__ z2_) {
    int g = blockIdx.y;
    int fb = blockIdx.z * 64;  // feature base (shorts) for this half
    const unsigned short* h = h_ + (size_t)g * Nn * 128;
    const int* off = off_ + g * (Nn + 1);
    const unsigned short* srcs = srcs_ + (size_t)g * En;
    unsigned short* z2 = z2_ + (size_t)g * Nn * 128;
    int node = blockIdx.x * 8 + (threadIdx.x >> 5);
    int lane = threadIdx.x & 31;
    int sub = lane >> 3;   // edge slot 0..3
    int fo = lane & 7;     // feature octile: feats fb + [fo*8, fo*8+8)
    int beg = off[node], end = off[node + 1];
    float acc[8] = {};
    for (int e = beg; e < end; e += 32) {
        int rem = end - e;
        int sj[8];
#pragma unroll
        for (int jj = 0; jj < 8; ++jj) sj[jj] = srcs[e + jj * 4 + sub];
#pragma unroll
        for (int jj = 0; jj < 8; ++jj) {
            if (jj * 4 + sub < rem) {
                v8s u = *(const v8s*)&h[(long)sj[jj] * 128 + fb + fo * 8];
#pragma unroll
                for (int q = 0; q < 8; ++q) acc[q] += bf2f((unsigned short)u[q]);
            }
        }
    }
#pragma unroll
    for (int q = 0; q < 8; ++q) {
        acc[q] += __shfl_xor(acc[q], 8, 32);
        acc[q] += __shfl_xor(acc[q], 16, 32);
    }
    if (sub == 0) {
        float dc = dinv_[g * Nn + node];
        v8s ow = *(const v8s*)&h[(long)node * 128 + fb + fo * 8];
        ushort4 o0, o1;
        o0.x = f2bf((acc[0] + bf2f((unsigned short)ow[0])) * dc);
        o0.y = f2bf((acc[1] + bf2f((unsigned short)ow[1])) * dc);
        o0.z = f2bf((acc[2] + bf2f((unsigned short)ow[2])) * dc);
        o0.w = f2bf((acc[3] + bf2f((unsigned short)ow[3])) * dc);
        o1.x = f2bf((acc[4] + bf2f((unsigned short)ow[4])) * dc);
        o1.y = f2bf((acc[5] + bf2f((unsigned short)ow[5])) * dc);
        o1.z = f2bf((acc[6] + bf2f((unsigned short)ow[6])) * dc);
        o1.w = f2bf((acc[7] + bf2f((unsigned short)ow[7])) * dc);
        *(ushort4*)&z2[(long)node * 128 + fb + fo * 8] = o0;
        *(ushort4*)&z2[(long)node * 128 + fb + fo * 8 + 4] = o1;
    }
}

// ---------------- MFMA mm, all graphs: out = relu(zin@W + b) [* dinv if SCALE] ----------------
template <int K, bool SCALE>
__global__ __launch_bounds__(256) void k_mmfma(const unsigned short* __restrict__ zin_,
                                               const float* __restrict__ W, const float* __restrict__ bias,
                                               const float* __restrict__ dinv_,
                                               unsigned short* __restrict__ outp_) {
    __shared__ __align__(16) unsigned short Wt[128 * (K + 8)];
    __shared__ __align__(16) unsigned short At[32 * (K + 8)];
    int g = blockIdx.y;
    const unsigned short* zin = zin_ + (size_t)g * Nn * K;
    const float* dinv = dinv_ + g * Nn;
    unsigned short* outp = outp_ + (size_t)g * Nn * 128;
    int t = threadIdx.x;
    int base = blockIdx.x * 32;

#pragma unroll
    for (int i = 0; i < K * 128 / 256; ++i) {
        int idx = i * 256 + t;
        int k = idx >> 7, n = idx & 127;
        Wt[n * (K + 8) + k] = f2bf(W[idx]);
    }
    {
        int r = t >> 3, cb = (t & 7) * (K / 8);
        long grow = base + r;
#pragma unroll
        for (int j = 0; j < K / 32; ++j) {
            ushort4 u = make_ushort4(0, 0, 0, 0);
            if (grow < Nn) u = *(const ushort4*)&zin[grow * K + cb + j * 4];
            *(ushort4*)&At[r * (K + 8) + cb + j * 4] = u;
        }
    }
    __syncthreads();

    int w = t >> 6, lane = t & 63;
    int wm = w & 1, wn = w >> 1;
    int m = lane & 15, q = lane >> 4;
    v4f acc[4] = {};
    const unsigned short* Ap = &At[(wm * 16 + m) * (K + 8) + q * 8];
    const unsigned short* Bp = &Wt[(wn * 64 + m) * (K + 8) + q * 8];
    const int rstep = 16 * (K + 8);
#pragma unroll
    for (int ks = 0; ks < K / 32; ++ks) {
        v8s a = *(const v8s*)(Ap + ks * 32);
        v8s b0 = *(const v8s*)(Bp + 0 * rstep + ks * 32);
        v8s b1 = *(const v8s*)(Bp + 1 * rstep + ks * 32);
        v8s b2 = *(const v8s*)(Bp + 2 * rstep + ks * 32);
        v8s b3 = *(const v8s*)(Bp + 3 * rstep + ks * 32);
        acc[0] = __builtin_amdgcn_mfma_f32_16x16x32_bf16(a, b0, acc[0], 0, 0, 0);
        acc[1] = __builtin_amdgcn_mfma_f32_16x16x32_bf16(a, b1, acc[1], 0, 0, 0);
        acc[2] = __builtin_amdgcn_mfma_f32_16x16x32_bf16(a, b2, acc[2], 0, 0, 0);
        acc[3] = __builtin_amdgcn_mfma_f32_16x16x32_bf16(a, b3, acc[3], 0, 0, 0);
    }

    int col0 = wn * 64 + m;
    int rbase = base + wm * 16 + q * 4;
    float dv[4];
#pragma unroll
    for (int rg = 0; rg < 4; ++rg)
        dv[rg] = SCALE ? ((rbase + rg < Nn) ? dinv[rbase + rg] : 1.f) : 1.f;
#pragma unroll
    for (int nt = 0; nt < 4; ++nt) {
        float bc = bias[col0 + nt * 16];
#pragma unroll
        for (int rg = 0; rg < 4; ++rg) {
            int row = rbase + rg;
            if (row < Nn) {
                float o = fmaxf(acc[nt][rg] + bc, 0.f);
                outp[(long)row * 128 + col0 + nt * 16] = f2bf(o * dv[rg]);
            }
        }
    }
}

// ---------------- segment mean pool (batch sorted), all graphs ----------------
__global__ __launch_bounds__(128) void k_pool(const unsigned short* __restrict__ y_, const int* __restrict__ bat,
                                              float* __restrict__ emb_sum, float* __restrict__ cnt) {
    int g = blockIdx.y;
    const unsigned short* y = y_ + (size_t)g * Nn * 128;
    const int* batch = bat + (size_t)g * Nn;
    int f = threadIdx.x;
    int start = blockIdx.x * 64;
    int end = min(start + 64, Nn);
    if (start >= Nn) return;
    float acc = 0.f;
    int cacc = 0;
    int cur = batch[start];
    for (int i = start; i < end; ++i) {
        int b = batch[i];
        if (b != cur) {
            atomicAdd(&emb_sum[(g * Bq + cur) * Hn + f], acc);
            if (f == 0) atomicAdd(&cnt[g * Bq + cur], (float)cacc);
            acc = 0.f; cacc = 0; cur = b;
        }
        acc += bf2f(y[(long)i * Hn + f]);
        cacc++;
    }
    atomicAdd(&emb_sum[(g * Bq + cur) * Hn + f], acc);
    if (f == 0) atomicAdd(&cnt[g * Bq + cur], (float)cacc);
}

// ---------------- whole MHA: one block per batch element b ----------------
__global__ __launch_bounds__(128) void k_attn(const float* __restrict__ emb_sum, const float* __restrict__ cnt,
                                              const float* __restrict__ ipw, const float* __restrict__ ipb,
                                              const float* __restrict__ opw, const float* __restrict__ opb,
                                              float* __restrict__ pooled) {
    int b = blockIdx.x;
    int f = threadIdx.x;
    __shared__ float es[4][128], qs[4][128], ks[4][128], vs[4][128], sc[128], cx[4][128];
#pragma unroll
    for (int g = 0; g < 4; ++g) {
        float c = cnt[g * Bq + b];
        es[g][f] = (c > 0.f) ? emb_sum[(g * Bq + b) * Hn + f] / c : 0.f;
    }
    __syncthreads();
#pragma unroll
    for (int g = 0; g < 4; ++g) {
        float q = ipb[f], k = ipb[Hn + f], v = ipb[2 * Hn + f];
        for (int j = 0; j < Hn; ++j) {
            float e = es[g][j];
            q += e * ipw[f * Hn + j];
            k += e * ipw[(Hn + f) * Hn + j];
            v += e * ipw[(2 * Hn + f) * Hn + j];
        }
        qs[g][f] = q; ks[g][f] = k; vs[g][f] = v;
    }
    __syncthreads();
    {
        int h = f >> 4, g = (f >> 2) & 3, kk = f & 3;
        float s = 0.f;
        for (int d = 0; d < 16; ++d) s += qs[g][h * 16 + d] * ks[kk][h * 16 + d];
        sc[f] = s * 0.25f;
    }
    __syncthreads();
    {
        int h = f >> 4;
#pragma unroll
        for (int g = 0; g < 4; ++g) {
            int bi = h * 16 + g * 4;
            float s0 = sc[bi], s1 = sc[bi + 1], s2 = sc[bi + 2], s3 = sc[bi + 3];
            float m = fmaxf(fmaxf(s0, s1), fmaxf(s2, s3));
            float e0 = __expf(s0 - m), e1 = __expf(s1 - m), e2 = __expf(s2 - m), e3 = __expf(s3 - m);
            float rinv = 1.f / (e0 + e1 + e2 + e3);
            cx[g][f] = (e0 * vs[0][f] + e1 * vs[1][f] + e2 * vs[2][f] + e3 * vs[3][f]) * rinv;
        }
    }
    __syncthreads();
#pragma unroll
    for (int g = 0; g < 4; ++g) {
        float a = opb[f];
        for (int j = 0; j < Hn; ++j) a += cx[g][j] * opw[f * Hn + j];
        atomicAdd(&pooled[g * Hn + f], a * (1.0f / Bq));
    }
}

// ---------------- final: out[g,n] = (pooled[g] . lin_w[n] + lin_b[n]) * 60 + 50 ----------------
__global__ __launch_bounds__(256) void k_final(const float* __restrict__ pooled, const float* __restrict__ lw,
                                               const float* __restrict__ lb, float* __restrict__ out) {
    __shared__ float ps[512];
    int t = threadIdx.x;
    ps[t] = pooled[t];
    ps[t + 256] = pooled[t + 256];
    __syncthreads();
    int wave = t >> 6, lane = t & 63;
    int n = blockIdx.x * 4 + wave;
    if (n >= NNODES) return;
    float2 w = *(const float2*)&lw[(long)n * 128 + lane * 2];
    float a0 = w.x * ps[0 * 128 + lane * 2] + w.y * ps[0 * 128 + lane * 2 + 1];
    float a1 = w.x * ps[1 * 128 + lane * 2] + w.y * ps[1 * 128 + lane * 2 + 1];
    float a2 = w.x * ps[2 * 128 + lane * 2] + w.y * ps[2 * 128 + lane * 2 + 1];
    float a3 = w.x * ps[3 * 128 + lane * 2] + w.y * ps[3 * 128 + lane * 2 + 1];
#pragma unroll
    for (int off = 32; off > 0; off >>= 1) {
        a0 += __shfl_down(a0, off);
        a1 += __shfl_down(a1, off);
        a2 += __shfl_down(a2, off);
        a3 += __shfl_down(a3, off);
    }
    if (lane == 0) {
        float bn = lb[n];
        out[0 * NNODES + n] = (a0 + bn) * 60.f + 50.f;
        out[1 * NNODES + n] = (a1 + bn) * 60.f + 50.f;
        out[2 * NNODES + n] = (a2 + bn) * 60.f + 50.f;
        out[3 * NNODES + n] = (a3 + bn) * 60.f + 50.f;
    }
}

extern "C" void kernel_launch(void* const* d_in, const int* in_sizes, int n_in,
                              void* d_out, int out_size, void* d_ws, size_t ws_size,
                              hipStream_t stream) {
    const float* x   = (const float*)d_in[0];
    const int*   ei  = (const int*)d_in[1];
    const int*   bat = (const int*)d_in[2];
    const float* W1  = (const float*)d_in[3];
    const float* b1  = (const float*)d_in[4];
    const float* W2  = (const float*)d_in[5];
    const float* b2  = (const float*)d_in[6];
    const float* ipw = (const float*)d_in[7];
    const float* ipb = (const float*)d_in[8];
    const float* opw = (const float*)d_in[9];
    const float* opb = (const float*)d_in[10];
    const float* lw  = (const float*)d_in[11];
    const float* lb  = (const float*)d_in[12];
    float* out = (float*)d_out;

    // workspace carve-up (~214 MB)
    char* p = (char*)d_ws;
    unsigned short* xbs = (unsigned short*)p;                 // [4][N,64]  bf16  25.6 MB
    unsigned short* z1  = (unsigned short*)(p + 25600000);    // [4][N,64]  bf16  25.6 MB
    unsigned short* y1b = (unsigned short*)(p + 51200000);    // [4][N,128] bf16  51.2 MB
    unsigned short* z2  = (unsigned short*)(p + 102400000);   // [4][N,128] bf16  51.2 MB
    unsigned int*   pairs = (unsigned int*)(p + 102400000);   // [4][E] uint 12.8 MB (alias z2; dead before agg2)
    unsigned short* y2b = (unsigned short*)(p + 153600000);   // [4][N,128] bf16  51.2 MB
    char* meta = p + 204800000;
    int*   off  = (int*)meta;                                 // [4][N+1]
    float* dinv = (float*)(off + 4 * (Nn + 1));               // [4][N]
    int*   btot  = (int*)(dinv + 4 * Nn);                     // [4][NBK]
    int*   bbase = btot + 4 * NBK;                            // [4][NBK]
    int*   bcur  = bbase + 4 * NBK;                           // [4][NBK]
    unsigned short* srcs = (unsigned short*)(bcur + 4 * NBK); // [4][E] ushort 6.4 MB
    float* emb    = (float*)(srcs + (size_t)4 * En);          // [G,B,H]
    float* cnt    = emb + Gn * Bq * Hn;                       // [G,B]
    float* pooled = cnt + Gn * Bq;                            // [G,H]

    hipMemsetAsync(btot, 0, 4 * NBK * sizeof(int), stream);
    hipMemsetAsync(emb, 0, Gn * Bq * Hn * sizeof(float), stream);
    hipMemsetAsync(cnt, 0, Gn * Bq * sizeof(float), stream);
    hipMemsetAsync(pooled, 0, Gn * Hn * sizeof(float), stream);

    const int agGrid = (Nn + 7) / 8;                 // 6250
    const int mmGrid = (Nn + 31) / 32;               // 1563
    const int plGrid = (Nn + 63) / 64;               // 782
    const int ctGrid = (Nn * 16 + 255) / 256;        // 3125

    // CSR build: totals -> bases -> bucketize -> fused (count+scan+off/dinv+fill)
    k_btot<<<dim3(EB, Gn), 256, 0, stream>>>(ei, btot);
    k_bbase<<<Gn, 256, 0, stream>>>(btot, bbase, bcur);
    k_bucket<<<dim3(EB, Gn), 256, 0, stream>>>(ei, bcur, pairs);
    k_fillb2<<<dim3(NBK, Gn), 256, 0, stream>>>(pairs, bbase, btot, off, dinv, srcs);

    // GCN layers, all graphs per launch; agg kernels feature-split via blockIdx.z
    // (z varies slowest in dispatch order -> halves execute mostly sequentially,
    //  halving the active gather footprint per phase for L2 residency)
    k_cast<<<dim3(ctGrid, Gn), 256, 0, stream>>>(x, dinv, xbs);
    k_agg1<<<dim3(agGrid, Gn, 2), 256, 0, stream>>>(xbs, off, srcs, dinv, z1);
    k_mmfma<64, true><<<dim3(mmGrid, Gn), 256, 0, stream>>>(z1, W1, b1, dinv, y1b);
    k_agg2<<<dim3(agGrid, Gn, 2), 256, 0, stream>>>(y1b, off, srcs, dinv, z2);
    k_mmfma<128, false><<<dim3(mmGrid, Gn), 256, 0, stream>>>(z2, W2, b2, dinv, y2b);
    k_pool<<<dim3(plGrid, Gn), 128, 0, stream>>>(y2b, bat, emb, cnt);

    k_attn<<<Bq, 128, 0, stream>>>(emb, cnt, ipw, ipb, opw, opb, pooled);
    k_final<<<(NNODES + 3) / 4, 256, 0, stream>>>(pooled, lw, lb, out);
}

// Round 5
// 552.106 us; speedup vs baseline: 1.0577x; 1.0577x over previous
//
#include <hip/hip_runtime.h>

#define Gn 4
#define Nn 50000
#define En 800000
#define Bq 32
#define F_IN 64
#define Hn 128
#define NNODES 50000
#define NBK 196     // dest buckets per graph (dest >> 8), 256 nodes each
#define EB 98       // edge chunks per graph (8192 edges each)

using v8s = __attribute__((ext_vector_type(8))) short;
using v4f = __attribute__((ext_vector_type(4))) float;

// ---- bf16 helpers (RNE) ----
__device__ __forceinline__ float bf2f(unsigned short u) {
    unsigned int x = ((unsigned int)u) << 16;
    float f; __builtin_memcpy(&f, &x, 4); return f;
}
__device__ __forceinline__ unsigned short f2bf(float f) {
    unsigned int x; __builtin_memcpy(&x, &f, 4);
    x = (x + 0x7fffu + ((x >> 16) & 1u)) >> 16;
    return (unsigned short)x;
}

// ---------------- phase 1: coarse bucket totals (bucket = dest>>8) ----------------
__global__ __launch_bounds__(256) void k_btot(const int* __restrict__ ei, int* __restrict__ btot) {
    __shared__ int h[NBK];
    int g = blockIdx.y;
    const int* col = ei + (size_t)g * 2 * En + En;
    for (int i = threadIdx.x; i < NBK; i += 256) h[i] = 0;
    __syncthreads();
    int e0 = blockIdx.x * 8192, e1 = min(e0 + 8192, En);
    for (int i = e0 / 4 + threadIdx.x; i < e1 / 4; i += 256) {
        int4 c = ((const int4*)col)[i];
        atomicAdd(&h[c.x >> 8], 1);
        atomicAdd(&h[c.y >> 8], 1);
        atomicAdd(&h[c.z >> 8], 1);
        atomicAdd(&h[c.w >> 8], 1);
    }
    __syncthreads();
    for (int i = threadIdx.x; i < NBK; i += 256)
        if (h[i]) atomicAdd(&btot[g * NBK + i], h[i]);
}

// ---------------- phase 2: scan bucket totals -> bases + global cursors ----------------
__global__ __launch_bounds__(256) void k_bbase(const int* __restrict__ btot, int* __restrict__ bbase,
                                               int* __restrict__ bcur) {
    __shared__ int s[256];
    int g = blockIdx.x, t = threadIdx.x;
    int v = (t < NBK) ? btot[g * NBK + t] : 0;
    s[t] = v;
    __syncthreads();
    for (int d = 1; d < 256; d <<= 1) {
        int u = (t >= d) ? s[t - d] : 0;
        __syncthreads();
        s[t] += u;
        __syncthreads();
    }
    if (t < NBK) { int b = s[t] - v; bbase[g * NBK + t] = b; bcur[g * NBK + t] = b; }
}

// ---------------- phase 3: bucketize edges into packed pairs (r<<16|c) ----------------
__global__ __launch_bounds__(256) void k_bucket(const int* __restrict__ ei, int* __restrict__ bcur,
                                                unsigned int* __restrict__ pairs) {
    __shared__ int h[NBK];
    __shared__ int gbase[NBK];
    int g = blockIdx.y;
    const int* row = ei + (size_t)g * 2 * En;
    const int* col = row + En;
    unsigned int* pg = pairs + (size_t)g * En;
    for (int i = threadIdx.x; i < NBK; i += 256) h[i] = 0;
    __syncthreads();
    int e0 = blockIdx.x * 8192, e1 = min(e0 + 8192, En);
    for (int i = e0 / 4 + threadIdx.x; i < e1 / 4; i += 256) {
        int4 c = ((const int4*)col)[i];
        atomicAdd(&h[c.x >> 8], 1);
        atomicAdd(&h[c.y >> 8], 1);
        atomicAdd(&h[c.z >> 8], 1);
        atomicAdd(&h[c.w >> 8], 1);
    }
    __syncthreads();
    for (int i = threadIdx.x; i < NBK; i += 256) {
        int cnt = h[i];
        gbase[i] = cnt ? atomicAdd(&bcur[g * NBK + i], cnt) : 0;
        h[i] = 0;  // becomes local cursor
    }
    __syncthreads();
    for (int i = e0 / 4 + threadIdx.x; i < e1 / 4; i += 256) {
        int4 c = ((const int4*)col)[i];
        int4 r = ((const int4*)row)[i];
        int p;
        p = gbase[c.x >> 8] + atomicAdd(&h[c.x >> 8], 1); pg[p] = ((unsigned)r.x << 16) | (unsigned)c.x;
        p = gbase[c.y >> 8] + atomicAdd(&h[c.y >> 8], 1); pg[p] = ((unsigned)r.y << 16) | (unsigned)c.y;
        p = gbase[c.z >> 8] + atomicAdd(&h[c.z >> 8], 1); pg[p] = ((unsigned)r.z << 16) | (unsigned)c.z;
        p = gbase[c.w >> 8] + atomicAdd(&h[c.w >> 8], 1); pg[p] = ((unsigned)r.w << 16) | (unsigned)c.w;
    }
}

// ---------------- phase 4 (fused): per-bucket count + scan -> off/dinv, then LDS-cursor fill ----------------
__global__ __launch_bounds__(256) void k_fillb2(const unsigned int* __restrict__ pairs,
                                                const int* __restrict__ bbase, const int* __restrict__ btot,
                                                int* __restrict__ off, float* __restrict__ dinv,
                                                unsigned short* __restrict__ srcs) {
    __shared__ int h[256], sc[256], curL[256];
    int g = blockIdx.y, b = blockIdx.x, t = threadIdx.x;
    int beg = bbase[g * NBK + b], cnt = btot[g * NBK + b];
    const unsigned int* pg = pairs + (size_t)g * En + beg;
    unsigned short* sg = srcs + (size_t)g * En;
    h[t] = 0;
    __syncthreads();
    for (int i = t; i < cnt; i += 256) atomicAdd(&h[pg[i] & 255], 1);
    __syncthreads();
    int d = h[t];
    sc[t] = d;
    __syncthreads();
    for (int dd = 1; dd < 256; dd <<= 1) {
        int u = (t >= dd) ? sc[t - dd] : 0;
        __syncthreads();
        sc[t] += u;
        __syncthreads();
    }
    int myoff = beg + sc[t] - d;  // exclusive
    int node = b * 256 + t;
    if (node < Nn) {
        off[g * (Nn + 1) + node] = myoff;
        dinv[g * Nn + node] = rsqrtf((float)d + 1.0f);
    }
    if (b == NBK - 1 && t == 255) off[g * (Nn + 1) + Nn] = beg + sc[255];
    curL[t] = myoff;
    __syncthreads();
    for (int i = t; i < cnt; i += 256) {
        unsigned int pr = pg[i];
        int pos = atomicAdd(&curL[pr & 255], 1);
        sg[pos] = (unsigned short)(pr >> 16);
    }
}

// ---------------- cast + pre-scale: xbs = bf16(x * dinv), all graphs ----------------
__global__ __launch_bounds__(256) void k_cast(const float* __restrict__ x, const float* __restrict__ dinv,
                                              unsigned short* __restrict__ xbs) {
    int g = blockIdx.y;
    int i = blockIdx.x * 256 + threadIdx.x;  // float4 index within graph
    if (i >= Nn * 16) return;
    float dc = dinv[g * Nn + (i >> 4)];
    float4 v = *(const float4*)&x[(size_t)g * Nn * 64 + i * 4];
    ushort4 u = make_ushort4(f2bf(v.x * dc), f2bf(v.y * dc), f2bf(v.z * dc), f2bf(v.w * dc));
    *(ushort4*)&xbs[(size_t)g * Nn * 64 + i * 4] = u;
}

// ---------------- agg 64-feat: branchless full-chunk gather (deep MLP) ----------------
__global__ __launch_bounds__(256, 4) void k_agg1(const unsigned short* __restrict__ xs_, const int* __restrict__ off_,
                                                 const unsigned short* __restrict__ srcs_,
                                                 const float* __restrict__ dinv_, unsigned short* __restrict__ z1_) {
    int g = blockIdx.y;
    const unsigned short* xs = xs_ + (size_t)g * Nn * 64;
    const int* off = off_ + g * (Nn + 1);
    const unsigned short* srcs = srcs_ + (size_t)g * En;
    unsigned short* z1 = z1_ + (size_t)g * Nn * 64;
    int node = blockIdx.x * 8 + (threadIdx.x >> 5);
    int lane = threadIdx.x & 31;
    int sub = lane >> 3;   // edge slot 0..3
    int fo = lane & 7;     // feature octile: feats [fo*8, fo*8+8)
    int beg = off[node], end = off[node + 1];
    float acc[8] = {};
    for (int e = beg; e < end; e += 32) {
        int rem = end - e;
        // unguarded sid pre-reads (may read a few bytes past this graph's srcs
        // slice; lands inside workspace, value only used when slot active)
        int sj[8];
#pragma unroll
        for (int jj = 0; jj < 8; ++jj) sj[jj] = srcs[e + jj * 4 + sub];
        // branchless: inactive slots gather row 0 (L1-resident broadcast line),
        // contribution masked by fma. All 8 loads issue up front -> deep MLP.
        v8s u[8]; float mk[8];
#pragma unroll
        for (int jj = 0; jj < 8; ++jj) {
            bool act = (jj * 4 + sub) < rem;
            long r = act ? (long)sj[jj] : 0L;
            u[jj] = *(const v8s*)&xs[r * 64 + fo * 8];
            mk[jj] = act ? 1.f : 0.f;
        }
#pragma unroll
        for (int jj = 0; jj < 8; ++jj) {
#pragma unroll
            for (int q = 0; q < 8; ++q) acc[q] += mk[jj] * bf2f((unsigned short)u[jj][q]);
        }
    }
#pragma unroll
    for (int q = 0; q < 8; ++q) {
        acc[q] += __shfl_xor(acc[q], 8, 32);
        acc[q] += __shfl_xor(acc[q], 16, 32);
    }
    if (sub == 0) {
        float dc = dinv_[g * Nn + node];
        v8s ow = *(const v8s*)&xs[(long)node * 64 + fo * 8];
        ushort4 o0, o1;
        o0.x = f2bf((acc[0] + bf2f((unsigned short)ow[0])) * dc);
        o0.y = f2bf((acc[1] + bf2f((unsigned short)ow[1])) * dc);
        o0.z = f2bf((acc[2] + bf2f((unsigned short)ow[2])) * dc);
        o0.w = f2bf((acc[3] + bf2f((unsigned short)ow[3])) * dc);
        o1.x = f2bf((acc[4] + bf2f((unsigned short)ow[4])) * dc);
        o1.y = f2bf((acc[5] + bf2f((unsigned short)ow[5])) * dc);
        o1.z = f2bf((acc[6] + bf2f((unsigned short)ow[6])) * dc);
        o1.w = f2bf((acc[7] + bf2f((unsigned short)ow[7])) * dc);
        *(ushort4*)&z1[(long)node * 64 + fo * 8] = o0;
        *(ushort4*)&z1[(long)node * 64 + fo * 8 + 4] = o1;
    }
}

// ---------------- agg 128-feat: branchless full-chunk gather (deep MLP) ----------------
__global__ __launch_bounds__(256, 4) void k_agg2(const unsigned short* __restrict__ h_, const int* __restrict__ off_,
                                                 const unsigned short* __restrict__ srcs_,
                                                 const float* __restrict__ dinv_, unsigned short* __restrict__ z2_) {
    int g = blockIdx.y;
    const unsigned short* h = h_ + (size_t)g * Nn * 128;
    const int* off = off_ + g * (Nn + 1);
    const unsigned short* srcs = srcs_ + (size_t)g * En;
    unsigned short* z2 = z2_ + (size_t)g * Nn * 128;
    int node = blockIdx.x * 8 + (threadIdx.x >> 5);
    int lane = threadIdx.x & 31;
    int sub = lane >> 3;   // edge slot 0..3
    int fo = lane & 7;     // feature 16-tile: feats [fo*16, fo*16+16)
    int beg = off[node], end = off[node + 1];
    float acc[16] = {};
    for (int e = beg; e < end; e += 32) {
        int rem = end - e;
        int sj[8];
#pragma unroll
        for (int jj = 0; jj < 8; ++jj) sj[jj] = srcs[e + jj * 4 + sub];
        v8s u0[8], u1[8]; float mk[8];
#pragma unroll
        for (int jj = 0; jj < 8; ++jj) {
            bool act = (jj * 4 + sub) < rem;
            long r = act ? (long)sj[jj] : 0L;
            const unsigned short* rp = &h[r * 128 + fo * 16];
            u0[jj] = *(const v8s*)rp;
            u1[jj] = *(const v8s*)(rp + 8);
            mk[jj] = act ? 1.f : 0.f;
        }
#pragma unroll
        for (int jj = 0; jj < 8; ++jj) {
#pragma unroll
            for (int q = 0; q < 8; ++q) acc[q] += mk[jj] * bf2f((unsigned short)u0[jj][q]);
#pragma unroll
            for (int q = 0; q < 8; ++q) acc[8 + q] += mk[jj] * bf2f((unsigned short)u1[jj][q]);
        }
    }
#pragma unroll
    for (int q = 0; q < 16; ++q) {
        acc[q] += __shfl_xor(acc[q], 8, 32);
        acc[q] += __shfl_xor(acc[q], 16, 32);
    }
    if (sub == 0) {
        float dc = dinv_[g * Nn + node];
        const unsigned short* op = &h[(long)node * 128 + fo * 16];
        unsigned short* zp = &z2[(long)node * 128 + fo * 16];
#pragma unroll
        for (int q4 = 0; q4 < 4; ++q4) {
            ushort4 ow = *(const ushort4*)(op + q4 * 4);
            ushort4 o;
            o.x = f2bf((acc[q4 * 4 + 0] + bf2f(ow.x)) * dc);
            o.y = f2bf((acc[q4 * 4 + 1] + bf2f(ow.y)) * dc);
            o.z = f2bf((acc[q4 * 4 + 2] + bf2f(ow.z)) * dc);
            o.w = f2bf((acc[q4 * 4 + 3] + bf2f(ow.w)) * dc);
            *(ushort4*)(zp + q4 * 4) = o;
        }
    }
}

// ---------------- MFMA mm, all graphs: out = relu(zin@W + b) [* dinv if SCALE] ----------------
template <int K, bool SCALE>
__global__ __launch_bounds__(256) void k_mmfma(const unsigned short* __restrict__ zin_,
                                               const float* __restrict__ W, const float* __restrict__ bias,
                                               const float* __restrict__ dinv_,
                                               unsigned short* __restrict__ outp_) {
    __shared__ __align__(16) unsigned short Wt[128 * (K + 8)];
    __shared__ __align__(16) unsigned short At[32 * (K + 8)];
    int g = blockIdx.y;
    const unsigned short* zin = zin_ + (size_t)g * Nn * K;
    const float* dinv = dinv_ + g * Nn;
    unsigned short* outp = outp_ + (size_t)g * Nn * 128;
    int t = threadIdx.x;
    int base = blockIdx.x * 32;

#pragma unroll
    for (int i = 0; i < K * 128 / 256; ++i) {
        int idx = i * 256 + t;
        int k = idx >> 7, n = idx & 127;
        Wt[n * (K + 8) + k] = f2bf(W[idx]);
    }
    {
        int r = t >> 3, cb = (t & 7) * (K / 8);
        long grow = base + r;
#pragma unroll
        for (int j = 0; j < K / 32; ++j) {
            ushort4 u = make_ushort4(0, 0, 0, 0);
            if (grow < Nn) u = *(const ushort4*)&zin[grow * K + cb + j * 4];
            *(ushort4*)&At[r * (K + 8) + cb + j * 4] = u;
        }
    }
    __syncthreads();

    int w = t >> 6, lane = t & 63;
    int wm = w & 1, wn = w >> 1;
    int m = lane & 15, q = lane >> 4;
    v4f acc[4] = {};
    const unsigned short* Ap = &At[(wm * 16 + m) * (K + 8) + q * 8];
    const unsigned short* Bp = &Wt[(wn * 64 + m) * (K + 8) + q * 8];
    const int rstep = 16 * (K + 8);
#pragma unroll
    for (int ks = 0; ks < K / 32; ++ks) {
        v8s a = *(const v8s*)(Ap + ks * 32);
        v8s b0 = *(const v8s*)(Bp + 0 * rstep + ks * 32);
        v8s b1 = *(const v8s*)(Bp + 1 * rstep + ks * 32);
        v8s b2 = *(const v8s*)(Bp + 2 * rstep + ks * 32);
        v8s b3 = *(const v8s*)(Bp + 3 * rstep + ks * 32);
        acc[0] = __builtin_amdgcn_mfma_f32_16x16x32_bf16(a, b0, acc[0], 0, 0, 0);
        acc[1] = __builtin_amdgcn_mfma_f32_16x16x32_bf16(a, b1, acc[1], 0, 0, 0);
        acc[2] = __builtin_amdgcn_mfma_f32_16x16x32_bf16(a, b2, acc[2], 0, 0, 0);
        acc[3] = __builtin_amdgcn_mfma_f32_16x16x32_bf16(a, b3, acc[3], 0, 0, 0);
    }

    int col0 = wn * 64 + m;
    int rbase = base + wm * 16 + q * 4;
    float dv[4];
#pragma unroll
    for (int rg = 0; rg < 4; ++rg)
        dv[rg] = SCALE ? ((rbase + rg < Nn) ? dinv[rbase + rg] : 1.f) : 1.f;
#pragma unroll
    for (int nt = 0; nt < 4; ++nt) {
        float bc = bias[col0 + nt * 16];
#pragma unroll
        for (int rg = 0; rg < 4; ++rg) {
            int row = rbase + rg;
            if (row < Nn) {
                float o = fmaxf(acc[nt][rg] + bc, 0.f);
                outp[(long)row * 128 + col0 + nt * 16] = f2bf(o * dv[rg]);
            }
        }
    }
}

// ---------------- segment mean pool (batch sorted), all graphs ----------------
__global__ __launch_bounds__(128) void k_pool(const unsigned short* __restrict__ y_, const int* __restrict__ bat,
                                              float* __restrict__ emb_sum, float* __restrict__ cnt) {
    int g = blockIdx.y;
    const unsigned short* y = y_ + (size_t)g * Nn * 128;
    const int* batch = bat + (size_t)g * Nn;
    int f = threadIdx.x;
    int start = blockIdx.x * 64;
    int end = min(start + 64, Nn);
    if (start >= Nn) return;
    float acc = 0.f;
    int cacc = 0;
    int cur = batch[start];
    for (int i = start; i < end; ++i) {
        int b = batch[i];
        if (b != cur) {
            atomicAdd(&emb_sum[(g * Bq + cur) * Hn + f], acc);
            if (f == 0) atomicAdd(&cnt[g * Bq + cur], (float)cacc);
            acc = 0.f; cacc = 0; cur = b;
        }
        acc += bf2f(y[(long)i * Hn + f]);
        cacc++;
    }
    atomicAdd(&emb_sum[(g * Bq + cur) * Hn + f], acc);
    if (f == 0) atomicAdd(&cnt[g * Bq + cur], (float)cacc);
}

// ---------------- whole MHA: one block per batch element b ----------------
__global__ __launch_bounds__(128) void k_attn(const float* __restrict__ emb_sum, const float* __restrict__ cnt,
                                              const float* __restrict__ ipw, const float* __restrict__ ipb,
                                              const float* __restrict__ opw, const float* __restrict__ opb,
                                              float* __restrict__ pooled) {
    int b = blockIdx.x;
    int f = threadIdx.x;
    __shared__ float es[4][128], qs[4][128], ks[4][128], vs[4][128], sc[128], cx[4][128];
#pragma unroll
    for (int g = 0; g < 4; ++g) {
        float c = cnt[g * Bq + b];
        es[g][f] = (c > 0.f) ? emb_sum[(g * Bq + b) * Hn + f] / c : 0.f;
    }
    __syncthreads();
#pragma unroll
    for (int g = 0; g < 4; ++g) {
        float q = ipb[f], k = ipb[Hn + f], v = ipb[2 * Hn + f];
        for (int j = 0; j < Hn; ++j) {
            float e = es[g][j];
            q += e * ipw[f * Hn + j];
            k += e * ipw[(Hn + f) * Hn + j];
            v += e * ipw[(2 * Hn + f) * Hn + j];
        }
        qs[g][f] = q; ks[g][f] = k; vs[g][f] = v;
    }
    __syncthreads();
    {
        int h = f >> 4, g = (f >> 2) & 3, kk = f & 3;
        float s = 0.f;
        for (int d = 0; d < 16; ++d) s += qs[g][h * 16 + d] * ks[kk][h * 16 + d];
        sc[f] = s * 0.25f;
    }
    __syncthreads();
    {
        int h = f >> 4;
#pragma unroll
        for (int g = 0; g < 4; ++g) {
            int bi = h * 16 + g * 4;
            float s0 = sc[bi], s1 = sc[bi + 1], s2 = sc[bi + 2], s3 = sc[bi + 3];
            float m = fmaxf(fmaxf(s0, s1), fmaxf(s2, s3));
            float e0 = __expf(s0 - m), e1 = __expf(s1 - m), e2 = __expf(s2 - m), e3 = __expf(s3 - m);
            float rinv = 1.f / (e0 + e1 + e2 + e3);
            cx[g][f] = (e0 * vs[0][f] + e1 * vs[1][f] + e2 * vs[2][f] + e3 * vs[3][f]) * rinv;
        }
    }
    __syncthreads();
#pragma unroll
    for (int g = 0; g < 4; ++g) {
        float a = opb[f];
        for (int j = 0; j < Hn; ++j) a += cx[g][j] * opw[f * Hn + j];
        atomicAdd(&pooled[g * Hn + f], a * (1.0f / Bq));
    }
}

// ---------------- final: out[g,n] = (pooled[g] . lin_w[n] + lin_b[n]) * 60 + 50 ----------------
__global__ __launch_bounds__(256) void k_final(const float* __restrict__ pooled, const float* __restrict__ lw,
                                               const float* __restrict__ lb, float* __restrict__ out) {
    __shared__ float ps[512];
    int t = threadIdx.x;
    ps[t] = pooled[t];
    ps[t + 256] = pooled[t + 256];
    __syncthreads();
    int wave = t >> 6, lane = t & 63;
    int n = blockIdx.x * 4 + wave;
    if (n >= NNODES) return;
    float2 w = *(const float2*)&lw[(long)n * 128 + lane * 2];
    float a0 = w.x * ps[0 * 128 + lane * 2] + w.y * ps[0 * 128 + lane * 2 + 1];
    float a1 = w.x * ps[1 * 128 + lane * 2] + w.y * ps[1 * 128 + lane * 2 + 1];
    float a2 = w.x * ps[2 * 128 + lane * 2] + w.y * ps[2 * 128 + lane * 2 + 1];
    float a3 = w.x * ps[3 * 128 + lane * 2] + w.y * ps[3 * 128 + lane * 2 + 1];
#pragma unroll
    for (int off = 32; off > 0; off >>= 1) {
        a0 += __shfl_down(a0, off);
        a1 += __shfl_down(a1, off);
        a2 += __shfl_down(a2, off);
        a3 += __shfl_down(a3, off);
    }
    if (lane == 0) {
        float bn = lb[n];
        out[0 * NNODES + n] = (a0 + bn) * 60.f + 50.f;
        out[1 * NNODES + n] = (a1 + bn) * 60.f + 50.f;
        out[2 * NNODES + n] = (a2 + bn) * 60.f + 50.f;
        out[3 * NNODES + n] = (a3 + bn) * 60.f + 50.f;
    }
}

extern "C" void kernel_launch(void* const* d_in, const int* in_sizes, int n_in,
                              void* d_out, int out_size, void* d_ws, size_t ws_size,
                              hipStream_t stream) {
    const float* x   = (const float*)d_in[0];
    const int*   ei  = (const int*)d_in[1];
    const int*   bat = (const int*)d_in[2];
    const float* W1  = (const float*)d_in[3];
    const float* b1  = (const float*)d_in[4];
    const float* W2  = (const float*)d_in[5];
    const float* b2  = (const float*)d_in[6];
    const float* ipw = (const float*)d_in[7];
    const float* ipb = (const float*)d_in[8];
    const float* opw = (const float*)d_in[9];
    const float* opb = (const float*)d_in[10];
    const float* lw  = (const float*)d_in[11];
    const float* lb  = (const float*)d_in[12];
    float* out = (float*)d_out;

    // workspace carve-up (~214 MB)
    char* p = (char*)d_ws;
    unsigned short* xbs = (unsigned short*)p;                 // [4][N,64]  bf16  25.6 MB
    unsigned short* z1  = (unsigned short*)(p + 25600000);    // [4][N,64]  bf16  25.6 MB
    unsigned short* y1b = (unsigned short*)(p + 51200000);    // [4][N,128] bf16  51.2 MB
    unsigned short* z2  = (unsigned short*)(p + 102400000);   // [4][N,128] bf16  51.2 MB
    unsigned int*   pairs = (unsigned int*)(p + 102400000);   // [4][E] uint 12.8 MB (alias z2; dead before agg2)
    unsigned short* y2b = (unsigned short*)(p + 153600000);   // [4][N,128] bf16  51.2 MB
    char* meta = p + 204800000;
    int*   off  = (int*)meta;                                 // [4][N+1]
    float* dinv = (float*)(off + 4 * (Nn + 1));               // [4][N]
    int*   btot  = (int*)(dinv + 4 * Nn);                     // [4][NBK]
    int*   bbase = btot + 4 * NBK;                            // [4][NBK]
    int*   bcur  = bbase + 4 * NBK;                           // [4][NBK]
    unsigned short* srcs = (unsigned short*)(bcur + 4 * NBK); // [4][E] ushort 6.4 MB
    float* emb    = (float*)(srcs + (size_t)4 * En);          // [G,B,H]
    float* cnt    = emb + Gn * Bq * Hn;                       // [G,B]
    float* pooled = cnt + Gn * Bq;                            // [G,H]

    hipMemsetAsync(btot, 0, 4 * NBK * sizeof(int), stream);
    hipMemsetAsync(emb, 0, Gn * Bq * Hn * sizeof(float), stream);
    hipMemsetAsync(cnt, 0, Gn * Bq * sizeof(float), stream);
    hipMemsetAsync(pooled, 0, Gn * Hn * sizeof(float), stream);

    const int agGrid = (Nn + 7) / 8;                 // 6250
    const int mmGrid = (Nn + 31) / 32;               // 1563
    const int plGrid = (Nn + 63) / 64;               // 782
    const int ctGrid = (Nn * 16 + 255) / 256;        // 3125

    // CSR build: totals -> bases -> bucketize -> fused (count+scan+off/dinv+fill)
    k_btot<<<dim3(EB, Gn), 256, 0, stream>>>(ei, btot);
    k_bbase<<<Gn, 256, 0, stream>>>(btot, bbase, bcur);
    k_bucket<<<dim3(EB, Gn), 256, 0, stream>>>(ei, bcur, pairs);
    k_fillb2<<<dim3(NBK, Gn), 256, 0, stream>>>(pairs, bbase, btot, off, dinv, srcs);

    // GCN layers, all graphs per launch
    k_cast<<<dim3(ctGrid, Gn), 256, 0, stream>>>(x, dinv, xbs);
    k_agg1<<<dim3(agGrid, Gn), 256, 0, stream>>>(xbs, off, srcs, dinv, z1);
    k_mmfma<64, true><<<dim3(mmGrid, Gn), 256, 0, stream>>>(z1, W1, b1, dinv, y1b);
    k_agg2<<<dim3(agGrid, Gn), 256, 0, stream>>>(y1b, off, srcs, dinv, z2);
    k_mmfma<128, false><<<dim3(mmGrid, Gn), 256, 0, stream>>>(z2, W2, b2, dinv, y2b);
    k_pool<<<dim3(plGrid, Gn), 128, 0, stream>>>(y2b, bat, emb, cnt);

    k_attn<<<Bq, 128, 0, stream>>>(emb, cnt, ipw, ipb, opw, opb, pooled);
    k_final<<<(NNODES + 3) / 4, 256, 0, stream>>>(pooled, lw, lb, out);
}

// Round 6
// 533.086 us; speedup vs baseline: 1.0954x; 1.0357x over previous
//
#include <hip/hip_runtime.h>

#define Gn 4
#define Nn 50000
#define En 800000
#define Bq 32
#define F_IN 64
#define Hn 128
#define NNODES 50000
#define NBK 196     // dest buckets per graph (dest >> 8), 256 nodes each
#define EB 98       // edge chunks per graph (8192 edges each)

using v8s = __attribute__((ext_vector_type(8))) short;
using v4f = __attribute__((ext_vector_type(4))) float;

// ---- bf16 helpers (RNE) ----
__device__ __forceinline__ float bf2f(unsigned short u) {
    unsigned int x = ((unsigned int)u) << 16;
    float f; __builtin_memcpy(&f, &x, 4); return f;
}
__device__ __forceinline__ unsigned short f2bf(float f) {
    unsigned int x; __builtin_memcpy(&x, &f, 4);
    x = (x + 0x7fffu + ((x >> 16) & 1u)) >> 16;
    return (unsigned short)x;
}

// ---------------- phase 1: coarse bucket totals (bucket = dest>>8) ----------------
__global__ __launch_bounds__(256) void k_btot(const int* __restrict__ ei, int* __restrict__ btot) {
    __shared__ int h[NBK];
    int g = blockIdx.y;
    const int* col = ei + (size_t)g * 2 * En + En;
    for (int i = threadIdx.x; i < NBK; i += 256) h[i] = 0;
    __syncthreads();
    int e0 = blockIdx.x * 8192, e1 = min(e0 + 8192, En);
    for (int i = e0 / 4 + threadIdx.x; i < e1 / 4; i += 256) {
        int4 c = ((const int4*)col)[i];
        atomicAdd(&h[c.x >> 8], 1);
        atomicAdd(&h[c.y >> 8], 1);
        atomicAdd(&h[c.z >> 8], 1);
        atomicAdd(&h[c.w >> 8], 1);
    }
    __syncthreads();
    for (int i = threadIdx.x; i < NBK; i += 256)
        if (h[i]) atomicAdd(&btot[g * NBK + i], h[i]);
}

// ---------------- phase 2: scan bucket totals -> bases + global cursors ----------------
__global__ __launch_bounds__(256) void k_bbase(const int* __restrict__ btot, int* __restrict__ bbase,
                                               int* __restrict__ bcur) {
    __shared__ int s[256];
    int g = blockIdx.x, t = threadIdx.x;
    int v = (t < NBK) ? btot[g * NBK + t] : 0;
    s[t] = v;
    __syncthreads();
    for (int d = 1; d < 256; d <<= 1) {
        int u = (t >= d) ? s[t - d] : 0;
        __syncthreads();
        s[t] += u;
        __syncthreads();
    }
    if (t < NBK) { int b = s[t] - v; bbase[g * NBK + t] = b; bcur[g * NBK + t] = b; }
}

// ---------------- phase 3: bucketize edges into packed pairs (r<<16|c) ----------------
__global__ __launch_bounds__(256) void k_bucket(const int* __restrict__ ei, int* __restrict__ bcur,
                                                unsigned int* __restrict__ pairs) {
    __shared__ int h[NBK];
    __shared__ int gbase[NBK];
    int g = blockIdx.y;
    const int* row = ei + (size_t)g * 2 * En;
    const int* col = row + En;
    unsigned int* pg = pairs + (size_t)g * En;
    for (int i = threadIdx.x; i < NBK; i += 256) h[i] = 0;
    __syncthreads();
    int e0 = blockIdx.x * 8192, e1 = min(e0 + 8192, En);
    for (int i = e0 / 4 + threadIdx.x; i < e1 / 4; i += 256) {
        int4 c = ((const int4*)col)[i];
        atomicAdd(&h[c.x >> 8], 1);
        atomicAdd(&h[c.y >> 8], 1);
        atomicAdd(&h[c.z >> 8], 1);
        atomicAdd(&h[c.w >> 8], 1);
    }
    __syncthreads();
    for (int i = threadIdx.x; i < NBK; i += 256) {
        int cnt = h[i];
        gbase[i] = cnt ? atomicAdd(&bcur[g * NBK + i], cnt) : 0;
        h[i] = 0;  // becomes local cursor
    }
    __syncthreads();
    for (int i = e0 / 4 + threadIdx.x; i < e1 / 4; i += 256) {
        int4 c = ((const int4*)col)[i];
        int4 r = ((const int4*)row)[i];
        int p;
        p = gbase[c.x >> 8] + atomicAdd(&h[c.x >> 8], 1); pg[p] = ((unsigned)r.x << 16) | (unsigned)c.x;
        p = gbase[c.y >> 8] + atomicAdd(&h[c.y >> 8], 1); pg[p] = ((unsigned)r.y << 16) | (unsigned)c.y;
        p = gbase[c.z >> 8] + atomicAdd(&h[c.z >> 8], 1); pg[p] = ((unsigned)r.z << 16) | (unsigned)c.z;
        p = gbase[c.w >> 8] + atomicAdd(&h[c.w >> 8], 1); pg[p] = ((unsigned)r.w << 16) | (unsigned)c.w;
    }
}

// ---------------- phase 4 (fused): per-bucket count + scan -> off/dinv, then LDS-cursor fill ----------------
__global__ __launch_bounds__(256) void k_fillb2(const unsigned int* __restrict__ pairs,
                                                const int* __restrict__ bbase, const int* __restrict__ btot,
                                                int* __restrict__ off, float* __restrict__ dinv,
                                                unsigned short* __restrict__ srcs) {
    __shared__ int h[256], sc[256], curL[256];
    int g = blockIdx.y, b = blockIdx.x, t = threadIdx.x;
    int beg = bbase[g * NBK + b], cnt = btot[g * NBK + b];
    const unsigned int* pg = pairs + (size_t)g * En + beg;
    unsigned short* sg = srcs + (size_t)g * En;
    h[t] = 0;
    __syncthreads();
    for (int i = t; i < cnt; i += 256) atomicAdd(&h[pg[i] & 255], 1);
    __syncthreads();
    int d = h[t];
    sc[t] = d;
    __syncthreads();
    for (int dd = 1; dd < 256; dd <<= 1) {
        int u = (t >= dd) ? sc[t - dd] : 0;
        __syncthreads();
        sc[t] += u;
        __syncthreads();
    }
    int myoff = beg + sc[t] - d;  // exclusive
    int node = b * 256 + t;
    if (node < Nn) {
        off[g * (Nn + 1) + node] = myoff;
        dinv[g * Nn + node] = rsqrtf((float)d + 1.0f);
    }
    if (b == NBK - 1 && t == 255) off[g * (Nn + 1) + Nn] = beg + sc[255];
    curL[t] = myoff;
    __syncthreads();
    for (int i = t; i < cnt; i += 256) {
        unsigned int pr = pg[i];
        int pos = atomicAdd(&curL[pr & 255], 1);
        sg[pos] = (unsigned short)(pr >> 16);
    }
}

// ---------------- cast + pre-scale: xbs = bf16(x * dinv), all graphs ----------------
__global__ __launch_bounds__(256) void k_cast(const float* __restrict__ x, const float* __restrict__ dinv,
                                              unsigned short* __restrict__ xbs) {
    int g = blockIdx.y;
    int i = blockIdx.x * 256 + threadIdx.x;  // float4 index within graph
    if (i >= Nn * 16) return;
    float dc = dinv[g * Nn + (i >> 4)];
    float4 v = *(const float4*)&x[(size_t)g * Nn * 64 + i * 4];
    ushort4 u = make_ushort4(f2bf(v.x * dc), f2bf(v.y * dc), f2bf(v.z * dc), f2bf(v.w * dc));
    *(ushort4*)&xbs[(size_t)g * Nn * 64 + i * 4] = u;
}

// ---------------- agg 64-feat: straight-line masked gather (no divergent load guard) ----------------
__global__ __launch_bounds__(256) void k_agg1(const unsigned short* __restrict__ xs_, const int* __restrict__ off_,
                                              const unsigned short* __restrict__ srcs_,
                                              const float* __restrict__ dinv_, unsigned short* __restrict__ z1_) {
    int g = blockIdx.y;
    const unsigned short* xs = xs_ + (size_t)g * Nn * 64;
    const int* off = off_ + g * (Nn + 1);
    const unsigned short* srcs = srcs_ + (size_t)g * En;
    unsigned short* z1 = z1_ + (size_t)g * Nn * 64;
    int node = blockIdx.x * 8 + (threadIdx.x >> 5);
    int lane = threadIdx.x & 31;
    int sub = lane >> 3;   // edge slot 0..3
    int fo = lane & 7;     // feature octile: feats [fo*8, fo*8+8)
    int beg = off[node], end = off[node + 1];
    float acc[8] = {};
    for (int e = beg; e < end; e += 32) {
        int rem = end - e;
        // unguarded sid pre-reads (may read a few bytes past this graph's srcs
        // slice; stays inside workspace, value only used when slot active)
        int sj[8];
#pragma unroll
        for (int jj = 0; jj < 8; ++jj) sj[jj] = srcs[e + jj * 4 + sub];
        // straight-line body: masked address (inactive -> row 0, L1-resident),
        // unconditional load, fma-masked accumulate. No branches -> compiler
        // can hoist/pipeline several gathers.
#pragma unroll
        for (int jj = 0; jj < 8; ++jj) {
            bool act = (jj * 4 + sub) < rem;
            long r = act ? (long)sj[jj] : 0L;
            v8s u = *(const v8s*)&xs[r * 64 + fo * 8];
            float m = act ? 1.f : 0.f;
#pragma unroll
            for (int q = 0; q < 8; ++q) acc[q] += m * bf2f((unsigned short)u[q]);
        }
    }
#pragma unroll
    for (int q = 0; q < 8; ++q) {
        acc[q] += __shfl_xor(acc[q], 8, 32);
        acc[q] += __shfl_xor(acc[q], 16, 32);
    }
    if (sub == 0) {
        float dc = dinv_[g * Nn + node];
        v8s ow = *(const v8s*)&xs[(long)node * 64 + fo * 8];
        ushort4 o0, o1;
        o0.x = f2bf((acc[0] + bf2f((unsigned short)ow[0])) * dc);
        o0.y = f2bf((acc[1] + bf2f((unsigned short)ow[1])) * dc);
        o0.z = f2bf((acc[2] + bf2f((unsigned short)ow[2])) * dc);
        o0.w = f2bf((acc[3] + bf2f((unsigned short)ow[3])) * dc);
        o1.x = f2bf((acc[4] + bf2f((unsigned short)ow[4])) * dc);
        o1.y = f2bf((acc[5] + bf2f((unsigned short)ow[5])) * dc);
        o1.z = f2bf((acc[6] + bf2f((unsigned short)ow[6])) * dc);
        o1.w = f2bf((acc[7] + bf2f((unsigned short)ow[7])) * dc);
        *(ushort4*)&z1[(long)node * 64 + fo * 8] = o0;
        *(ushort4*)&z1[(long)node * 64 + fo * 8 + 4] = o1;
    }
}

// ---------------- agg 128-feat: straight-line masked gather (no divergent load guard) ----------------
__global__ __launch_bounds__(256) void k_agg2(const unsigned short* __restrict__ h_, const int* __restrict__ off_,
                                              const unsigned short* __restrict__ srcs_,
                                              const float* __restrict__ dinv_, unsigned short* __restrict__ z2_) {
    int g = blockIdx.y;
    const unsigned short* h = h_ + (size_t)g * Nn * 128;
    const int* off = off_ + g * (Nn + 1);
    const unsigned short* srcs = srcs_ + (size_t)g * En;
    unsigned short* z2 = z2_ + (size_t)g * Nn * 128;
    int node = blockIdx.x * 8 + (threadIdx.x >> 5);
    int lane = threadIdx.x & 31;
    int sub = lane >> 3;   // edge slot 0..3
    int fo = lane & 7;     // feature 16-tile: feats [fo*16, fo*16+16)
    int beg = off[node], end = off[node + 1];
    float acc[16] = {};
    for (int e = beg; e < end; e += 32) {
        int rem = end - e;
        int sj[8];
#pragma unroll
        for (int jj = 0; jj < 8; ++jj) sj[jj] = srcs[e + jj * 4 + sub];
#pragma unroll
        for (int jj = 0; jj < 8; ++jj) {
            bool act = (jj * 4 + sub) < rem;
            long r = act ? (long)sj[jj] : 0L;
            const unsigned short* rp = &h[r * 128 + fo * 16];
            v8s u0 = *(const v8s*)rp;
            v8s u1 = *(const v8s*)(rp + 8);
            float m = act ? 1.f : 0.f;
#pragma unroll
            for (int q = 0; q < 8; ++q) acc[q] += m * bf2f((unsigned short)u0[q]);
#pragma unroll
            for (int q = 0; q < 8; ++q) acc[8 + q] += m * bf2f((unsigned short)u1[q]);
        }
    }
#pragma unroll
    for (int q = 0; q < 16; ++q) {
        acc[q] += __shfl_xor(acc[q], 8, 32);
        acc[q] += __shfl_xor(acc[q], 16, 32);
    }
    if (sub == 0) {
        float dc = dinv_[g * Nn + node];
        const unsigned short* op = &h[(long)node * 128 + fo * 16];
        unsigned short* zp = &z2[(long)node * 128 + fo * 16];
#pragma unroll
        for (int q4 = 0; q4 < 4; ++q4) {
            ushort4 ow = *(const ushort4*)(op + q4 * 4);
            ushort4 o;
            o.x = f2bf((acc[q4 * 4 + 0] + bf2f(ow.x)) * dc);
            o.y = f2bf((acc[q4 * 4 + 1] + bf2f(ow.y)) * dc);
            o.z = f2bf((acc[q4 * 4 + 2] + bf2f(ow.z)) * dc);
            o.w = f2bf((acc[q4 * 4 + 3] + bf2f(ow.w)) * dc);
            *(ushort4*)(zp + q4 * 4) = o;
        }
    }
}

// ---------------- MFMA mm, all graphs: out = relu(zin@W + b) [* dinv if SCALE] ----------------
template <int K, bool SCALE>
__global__ __launch_bounds__(256) void k_mmfma(const unsigned short* __restrict__ zin_,
                                               const float* __restrict__ W, const float* __restrict__ bias,
                                               const float* __restrict__ dinv_,
                                               unsigned short* __restrict__ outp_) {
    __shared__ __align__(16) unsigned short Wt[128 * (K + 8)];
    __shared__ __align__(16) unsigned short At[32 * (K + 8)];
    int g = blockIdx.y;
    const unsigned short* zin = zin_ + (size_t)g * Nn * K;
    const float* dinv = dinv_ + g * Nn;
    unsigned short* outp = outp_ + (size_t)g * Nn * 128;
    int t = threadIdx.x;
    int base = blockIdx.x * 32;

#pragma unroll
    for (int i = 0; i < K * 128 / 256; ++i) {
        int idx = i * 256 + t;
        int k = idx >> 7, n = idx & 127;
        Wt[n * (K + 8) + k] = f2bf(W[idx]);
    }
    {
        int r = t >> 3, cb = (t & 7) * (K / 8);
        long grow = base + r;
#pragma unroll
        for (int j = 0; j < K / 32; ++j) {
            ushort4 u = make_ushort4(0, 0, 0, 0);
            if (grow < Nn) u = *(const ushort4*)&zin[grow * K + cb + j * 4];
            *(ushort4*)&At[r * (K + 8) + cb + j * 4] = u;
        }
    }
    __syncthreads();

    int w = t >> 6, lane = t & 63;
    int wm = w & 1, wn = w >> 1;
    int m = lane & 15, q = lane >> 4;
    v4f acc[4] = {};
    const unsigned short* Ap = &At[(wm * 16 + m) * (K + 8) + q * 8];
    const unsigned short* Bp = &Wt[(wn * 64 + m) * (K + 8) + q * 8];
    const int rstep = 16 * (K + 8);
#pragma unroll
    for (int ks = 0; ks < K / 32; ++ks) {
        v8s a = *(const v8s*)(Ap + ks * 32);
        v8s b0 = *(const v8s*)(Bp + 0 * rstep + ks * 32);
        v8s b1 = *(const v8s*)(Bp + 1 * rstep + ks * 32);
        v8s b2 = *(const v8s*)(Bp + 2 * rstep + ks * 32);
        v8s b3 = *(const v8s*)(Bp + 3 * rstep + ks * 32);
        acc[0] = __builtin_amdgcn_mfma_f32_16x16x32_bf16(a, b0, acc[0], 0, 0, 0);
        acc[1] = __builtin_amdgcn_mfma_f32_16x16x32_bf16(a, b1, acc[1], 0, 0, 0);
        acc[2] = __builtin_amdgcn_mfma_f32_16x16x32_bf16(a, b2, acc[2], 0, 0, 0);
        acc[3] = __builtin_amdgcn_mfma_f32_16x16x32_bf16(a, b3, acc[3], 0, 0, 0);
    }

    int col0 = wn * 64 + m;
    int rbase = base + wm * 16 + q * 4;
    float dv[4];
#pragma unroll
    for (int rg = 0; rg < 4; ++rg)
        dv[rg] = SCALE ? ((rbase + rg < Nn) ? dinv[rbase + rg] : 1.f) : 1.f;
#pragma unroll
    for (int nt = 0; nt < 4; ++nt) {
        float bc = bias[col0 + nt * 16];
#pragma unroll
        for (int rg = 0; rg < 4; ++rg) {
            int row = rbase + rg;
            if (row < Nn) {
                float o = fmaxf(acc[nt][rg] + bc, 0.f);
                outp[(long)row * 128 + col0 + nt * 16] = f2bf(o * dv[rg]);
            }
        }
    }
}

// ---------------- segment mean pool (batch sorted), all graphs ----------------
__global__ __launch_bounds__(128) void k_pool(const unsigned short* __restrict__ y_, const int* __restrict__ bat,
                                              float* __restrict__ emb_sum, float* __restrict__ cnt) {
    int g = blockIdx.y;
    const unsigned short* y = y_ + (size_t)g * Nn * 128;
    const int* batch = bat + (size_t)g * Nn;
    int f = threadIdx.x;
    int start = blockIdx.x * 64;
    int end = min(start + 64, Nn);
    if (start >= Nn) return;
    float acc = 0.f;
    int cacc = 0;
    int cur = batch[start];
    for (int i = start; i < end; ++i) {
        int b = batch[i];
        if (b != cur) {
            atomicAdd(&emb_sum[(g * Bq + cur) * Hn + f], acc);
            if (f == 0) atomicAdd(&cnt[g * Bq + cur], (float)cacc);
            acc = 0.f; cacc = 0; cur = b;
        }
        acc += bf2f(y[(long)i * Hn + f]);
        cacc++;
    }
    atomicAdd(&emb_sum[(g * Bq + cur) * Hn + f], acc);
    if (f == 0) atomicAdd(&cnt[g * Bq + cur], (float)cacc);
}

// ---------------- whole MHA: one block per batch element b ----------------
__global__ __launch_bounds__(128) void k_attn(const float* __restrict__ emb_sum, const float* __restrict__ cnt,
                                              const float* __restrict__ ipw, const float* __restrict__ ipb,
                                              const float* __restrict__ opw, const float* __restrict__ opb,
                                              float* __restrict__ pooled) {
    int b = blockIdx.x;
    int f = threadIdx.x;
    __shared__ float es[4][128], qs[4][128], ks[4][128], vs[4][128], sc[128], cx[4][128];
#pragma unroll
    for (int g = 0; g < 4; ++g) {
        float c = cnt[g * Bq + b];
        es[g][f] = (c > 0.f) ? emb_sum[(g * Bq + b) * Hn + f] / c : 0.f;
    }
    __syncthreads();
#pragma unroll
    for (int g = 0; g < 4; ++g) {
        float q = ipb[f], k = ipb[Hn + f], v = ipb[2 * Hn + f];
        for (int j = 0; j < Hn; ++j) {
            float e = es[g][j];
            q += e * ipw[f * Hn + j];
            k += e * ipw[(Hn + f) * Hn + j];
            v += e * ipw[(2 * Hn + f) * Hn + j];
        }
        qs[g][f] = q; ks[g][f] = k; vs[g][f] = v;
    }
    __syncthreads();
    {
        int h = f >> 4, g = (f >> 2) & 3, kk = f & 3;
        float s = 0.f;
        for (int d = 0; d < 16; ++d) s += qs[g][h * 16 + d] * ks[kk][h * 16 + d];
        sc[f] = s * 0.25f;
    }
    __syncthreads();
    {
        int h = f >> 4;
#pragma unroll
        for (int g = 0; g < 4; ++g) {
            int bi = h * 16 + g * 4;
            float s0 = sc[bi], s1 = sc[bi + 1], s2 = sc[bi + 2], s3 = sc[bi + 3];
            float m = fmaxf(fmaxf(s0, s1), fmaxf(s2, s3));
            float e0 = __expf(s0 - m), e1 = __expf(s1 - m), e2 = __expf(s2 - m), e3 = __expf(s3 - m);
            float rinv = 1.f / (e0 + e1 + e2 + e3);
            cx[g][f] = (e0 * vs[0][f] + e1 * vs[1][f] + e2 * vs[2][f] + e3 * vs[3][f]) * rinv;
        }
    }
    __syncthreads();
#pragma unroll
    for (int g = 0; g < 4; ++g) {
        float a = opb[f];
        for (int j = 0; j < Hn; ++j) a += cx[g][j] * opw[f * Hn + j];
        atomicAdd(&pooled[g * Hn + f], a * (1.0f / Bq));
    }
}

// ---------------- final: out[g,n] = (pooled[g] . lin_w[n] + lin_b[n]) * 60 + 50 ----------------
__global__ __launch_bounds__(256) void k_final(const float* __restrict__ pooled, const float* __restrict__ lw,
                                               const float* __restrict__ lb, float* __restrict__ out) {
    __shared__ float ps[512];
    int t = threadIdx.x;
    ps[t] = pooled[t];
    ps[t + 256] = pooled[t + 256];
    __syncthreads();
    int wave = t >> 6, lane = t & 63;
    int n = blockIdx.x * 4 + wave;
    if (n >= NNODES) return;
    float2 w = *(const float2*)&lw[(long)n * 128 + lane * 2];
    float a0 = w.x * ps[0 * 128 + lane * 2] + w.y * ps[0 * 128 + lane * 2 + 1];
    float a1 = w.x * ps[1 * 128 + lane * 2] + w.y * ps[1 * 128 + lane * 2 + 1];
    float a2 = w.x * ps[2 * 128 + lane * 2] + w.y * ps[2 * 128 + lane * 2 + 1];
    float a3 = w.x * ps[3 * 128 + lane * 2] + w.y * ps[3 * 128 + lane * 2 + 1];
#pragma unroll
    for (int off = 32; off > 0; off >>= 1) {
        a0 += __shfl_down(a0, off);
        a1 += __shfl_down(a1, off);
        a2 += __shfl_down(a2, off);
        a3 += __shfl_down(a3, off);
    }
    if (lane == 0) {
        float bn = lb[n];
        out[0 * NNODES + n] = (a0 + bn) * 60.f + 50.f;
        out[1 * NNODES + n] = (a1 + bn) * 60.f + 50.f;
        out[2 * NNODES + n] = (a2 + bn) * 60.f + 50.f;
        out[3 * NNODES + n] = (a3 + bn) * 60.f + 50.f;
    }
}

extern "C" void kernel_launch(void* const* d_in, const int* in_sizes, int n_in,
                              void* d_out, int out_size, void* d_ws, size_t ws_size,
                              hipStream_t stream) {
    const float* x   = (const float*)d_in[0];
    const int*   ei  = (const int*)d_in[1];
    const int*   bat = (const int*)d_in[2];
    const float* W1  = (const float*)d_in[3];
    const float* b1  = (const float*)d_in[4];
    const float* W2  = (const float*)d_in[5];
    const float* b2  = (const float*)d_in[6];
    const float* ipw = (const float*)d_in[7];
    const float* ipb = (const float*)d_in[8];
    const float* opw = (const float*)d_in[9];
    const float* opb = (const float*)d_in[10];
    const float* lw  = (const float*)d_in[11];
    const float* lb  = (const float*)d_in[12];
    float* out = (float*)d_out;

    // workspace carve-up (~214 MB)
    char* p = (char*)d_ws;
    unsigned short* xbs = (unsigned short*)p;                 // [4][N,64]  bf16  25.6 MB
    unsigned short* z1  = (unsigned short*)(p + 25600000);    // [4][N,64]  bf16  25.6 MB
    unsigned short* y1b = (unsigned short*)(p + 51200000);    // [4][N,128] bf16  51.2 MB
    unsigned short* z2  = (unsigned short*)(p + 102400000);   // [4][N,128] bf16  51.2 MB
    unsigned int*   pairs = (unsigned int*)(p + 102400000);   // [4][E] uint 12.8 MB (alias z2; dead before agg2)
    unsigned short* y2b = (unsigned short*)(p + 153600000);   // [4][N,128] bf16  51.2 MB
    char* meta = p + 204800000;
    int*   off  = (int*)meta;                                 // [4][N+1]
    float* dinv = (float*)(off + 4 * (Nn + 1));               // [4][N]
    int*   btot  = (int*)(dinv + 4 * Nn);                     // [4][NBK]
    int*   bbase = btot + 4 * NBK;                            // [4][NBK]
    int*   bcur  = bbase + 4 * NBK;                           // [4][NBK]
    unsigned short* srcs = (unsigned short*)(bcur + 4 * NBK); // [4][E] ushort 6.4 MB
    float* emb    = (float*)(srcs + (size_t)4 * En);          // [G,B,H]
    float* cnt    = emb + Gn * Bq * Hn;                       // [G,B]
    float* pooled = cnt + Gn * Bq;                            // [G,H]

    hipMemsetAsync(btot, 0, 4 * NBK * sizeof(int), stream);
    hipMemsetAsync(emb, 0, Gn * Bq * Hn * sizeof(float), stream);
    hipMemsetAsync(cnt, 0, Gn * Bq * sizeof(float), stream);
    hipMemsetAsync(pooled, 0, Gn * Hn * sizeof(float), stream);

    const int agGrid = (Nn + 7) / 8;                 // 6250
    const int mmGrid = (Nn + 31) / 32;               // 1563
    const int plGrid = (Nn + 63) / 64;               // 782
    const int ctGrid = (Nn * 16 + 255) / 256;        // 3125

    // CSR build: totals -> bases -> bucketize -> fused (count+scan+off/dinv+fill)
    k_btot<<<dim3(EB, Gn), 256, 0, stream>>>(ei, btot);
    k_bbase<<<Gn, 256, 0, stream>>>(btot, bbase, bcur);
    k_bucket<<<dim3(EB, Gn), 256, 0, stream>>>(ei, bcur, pairs);
    k_fillb2<<<dim3(NBK, Gn), 256, 0, stream>>>(pairs, bbase, btot, off, dinv, srcs);

    // GCN layers, all graphs per launch
    k_cast<<<dim3(ctGrid, Gn), 256, 0, stream>>>(x, dinv, xbs);
    k_agg1<<<dim3(agGrid, Gn), 256, 0, stream>>>(xbs, off, srcs, dinv, z1);
    k_mmfma<64, true><<<dim3(mmGrid, Gn), 256, 0, stream>>>(z1, W1, b1, dinv, y1b);
    k_agg2<<<dim3(agGrid, Gn), 256, 0, stream>>>(y1b, off, srcs, dinv, z2);
    k_mmfma<128, false><<<dim3(mmGrid, Gn), 256, 0, stream>>>(z2, W2, b2, dinv, y2b);
    k_pool<<<dim3(plGrid, Gn), 128, 0, stream>>>(y2b, bat, emb, cnt);

    k_attn<<<Bq, 128, 0, stream>>>(emb, cnt, ipw, ipb, opw, opb, pooled);
    k_final<<<(NNODES + 3) / 4, 256, 0, stream>>>(pooled, lw, lb, out);
}

// Round 7
// 526.676 us; speedup vs baseline: 1.1088x; 1.0122x over previous
//
#include <hip/hip_runtime.h>

#define Gn 4
#define Nn 50000
#define En 800000
#define Bq 32
#define F_IN 64
#define Hn 128
#define NNODES 50000
#define NBK 196     // dest buckets per graph (dest >> 8), 256 nodes each
#define EB 98       // edge chunks per graph (8192 edges each)

using v8s = __attribute__((ext_vector_type(8))) short;
using v4f = __attribute__((ext_vector_type(4))) float;

// ---- bf16 helpers (RNE) ----
__device__ __forceinline__ float bf2f(unsigned short u) {
    unsigned int x = ((unsigned int)u) << 16;
    float f; __builtin_memcpy(&f, &x, 4); return f;
}
__device__ __forceinline__ unsigned short f2bf(float f) {
    unsigned int x; __builtin_memcpy(&x, &f, 4);
    x = (x + 0x7fffu + ((x >> 16) & 1u)) >> 16;
    return (unsigned short)x;
}

// ---------------- phase 1: coarse bucket totals + per-chunk histograms ----------------
__global__ __launch_bounds__(256) void k_btot(const int* __restrict__ ei, int* __restrict__ btot,
                                              int* __restrict__ chist) {
    __shared__ int h[NBK];
    int g = blockIdx.y;
    const int* col = ei + (size_t)g * 2 * En + En;
    for (int i = threadIdx.x; i < NBK; i += 256) h[i] = 0;
    __syncthreads();
    int e0 = blockIdx.x * 8192, e1 = min(e0 + 8192, En);
    for (int i = e0 / 4 + threadIdx.x; i < e1 / 4; i += 256) {
        int4 c = ((const int4*)col)[i];
        atomicAdd(&h[c.x >> 8], 1);
        atomicAdd(&h[c.y >> 8], 1);
        atomicAdd(&h[c.z >> 8], 1);
        atomicAdd(&h[c.w >> 8], 1);
    }
    __syncthreads();
    int* ch = chist + ((size_t)g * EB + blockIdx.x) * NBK;
    for (int i = threadIdx.x; i < NBK; i += 256) {
        int v = h[i];
        ch[i] = v;
        if (v) atomicAdd(&btot[g * NBK + i], v);
    }
}

// ---------------- phase 2: scan bucket totals -> bases + global cursors ----------------
__global__ __launch_bounds__(256) void k_bbase(const int* __restrict__ btot, int* __restrict__ bbase,
                                               int* __restrict__ bcur) {
    __shared__ int s[256];
    int g = blockIdx.x, t = threadIdx.x;
    int v = (t < NBK) ? btot[g * NBK + t] : 0;
    s[t] = v;
    __syncthreads();
    for (int d = 1; d < 256; d <<= 1) {
        int u = (t >= d) ? s[t - d] : 0;
        __syncthreads();
        s[t] += u;
        __syncthreads();
    }
    if (t < NBK) { int b = s[t] - v; bbase[g * NBK + t] = b; bcur[g * NBK + t] = b; }
}

// ---------------- phase 3: bucketize (reuses per-chunk histograms; one edge scan) ----------------
__global__ __launch_bounds__(256) void k_bucket(const int* __restrict__ ei, int* __restrict__ bcur,
                                                unsigned int* __restrict__ pairs,
                                                const int* __restrict__ chist) {
    __shared__ int h[NBK];
    __shared__ int gbase[NBK];
    int g = blockIdx.y;
    const int* row = ei + (size_t)g * 2 * En;
    const int* col = row + En;
    unsigned int* pg = pairs + (size_t)g * En;
    const int* ch = chist + ((size_t)g * EB + blockIdx.x) * NBK;
    for (int i = threadIdx.x; i < NBK; i += 256) {
        int cnt = ch[i];
        gbase[i] = cnt ? atomicAdd(&bcur[g * NBK + i], cnt) : 0;
        h[i] = 0;  // local cursor
    }
    __syncthreads();
    int e0 = blockIdx.x * 8192, e1 = min(e0 + 8192, En);
    for (int i = e0 / 4 + threadIdx.x; i < e1 / 4; i += 256) {
        int4 c = ((const int4*)col)[i];
        int4 r = ((const int4*)row)[i];
        int p;
        p = gbase[c.x >> 8] + atomicAdd(&h[c.x >> 8], 1); pg[p] = ((unsigned)r.x << 16) | (unsigned)c.x;
        p = gbase[c.y >> 8] + atomicAdd(&h[c.y >> 8], 1); pg[p] = ((unsigned)r.y << 16) | (unsigned)c.y;
        p = gbase[c.z >> 8] + atomicAdd(&h[c.z >> 8], 1); pg[p] = ((unsigned)r.z << 16) | (unsigned)c.z;
        p = gbase[c.w >> 8] + atomicAdd(&h[c.w >> 8], 1); pg[p] = ((unsigned)r.w << 16) | (unsigned)c.w;
    }
}

// ---------------- phase 4 (fused): per-bucket count + scan -> off/dinv, then LDS-cursor fill ----------------
__global__ __launch_bounds__(256) void k_fillb2(const unsigned int* __restrict__ pairs,
                                                const int* __restrict__ bbase, const int* __restrict__ btot,
                                                int* __restrict__ off, float* __restrict__ dinv,
                                                unsigned short* __restrict__ srcs) {
    __shared__ int h[256], sc[256], curL[256];
    int g = blockIdx.y, b = blockIdx.x, t = threadIdx.x;
    int beg = bbase[g * NBK + b], cnt = btot[g * NBK + b];
    const unsigned int* pg = pairs + (size_t)g * En + beg;
    unsigned short* sg = srcs + (size_t)g * En;
    h[t] = 0;
    __syncthreads();
    for (int i = t; i < cnt; i += 256) atomicAdd(&h[pg[i] & 255], 1);
    __syncthreads();
    int d = h[t];
    sc[t] = d;
    __syncthreads();
    for (int dd = 1; dd < 256; dd <<= 1) {
        int u = (t >= dd) ? sc[t - dd] : 0;
        __syncthreads();
        sc[t] += u;
        __syncthreads();
    }
    int myoff = beg + sc[t] - d;  // exclusive
    int node = b * 256 + t;
    if (node < Nn) {
        off[g * (Nn + 1) + node] = myoff;
        dinv[g * Nn + node] = rsqrtf((float)d + 1.0f);
    }
    if (b == NBK - 1 && t == 255) off[g * (Nn + 1) + Nn] = beg + sc[255];
    curL[t] = myoff;
    __syncthreads();
    for (int i = t; i < cnt; i += 256) {
        unsigned int pr = pg[i];
        int pos = atomicAdd(&curL[pr & 255], 1);
        sg[pos] = (unsigned short)(pr >> 16);
    }
}

// ---------------- cast + pre-scale: xbs = bf16(x * dinv), all graphs ----------------
__global__ __launch_bounds__(256) void k_cast(const float* __restrict__ x, const float* __restrict__ dinv,
                                              unsigned short* __restrict__ xbs) {
    int g = blockIdx.y;
    int i = blockIdx.x * 256 + threadIdx.x;  // float4 index within graph
    if (i >= Nn * 16) return;
    float dc = dinv[g * Nn + (i >> 4)];
    float4 v = *(const float4*)&x[(size_t)g * Nn * 64 + i * 4];
    ushort4 u = make_ushort4(f2bf(v.x * dc), f2bf(v.y * dc), f2bf(v.z * dc), f2bf(v.w * dc));
    *(ushort4*)&xbs[(size_t)g * Nn * 64 + i * 4] = u;
}

// ---------------- agg 64-feat: rolling 4-edge steps, 1-deep gather pipeline ----------------
__global__ __launch_bounds__(256) void k_agg1(const unsigned short* __restrict__ xs_, const int* __restrict__ off_,
                                              const unsigned short* __restrict__ srcs_,
                                              const float* __restrict__ dinv_, unsigned short* __restrict__ z1_) {
    int g = blockIdx.y;
    const unsigned short* xs = xs_ + (size_t)g * Nn * 64;
    const int* off = off_ + g * (Nn + 1);
    const unsigned short* srcs = srcs_ + (size_t)g * En;
    unsigned short* z1 = z1_ + (size_t)g * Nn * 64;
    int node = blockIdx.x * 8 + (threadIdx.x >> 5);
    int lane = threadIdx.x & 31;
    int sub = lane >> 3;   // edge slot 0..3
    int fo = lane & 7;     // feature octile: feats [fo*8, fo*8+8)
    int beg = off[node], end = off[node + 1];
    int d = end - beg;
    int dm1 = max(d - 1, 0);
    int nst = (d + 3) >> 2;            // uniform step count within 32-lane group
    float acc[8] = {};
    // rolling pipeline: sid-clamped (always-valid) loads, gather for step st+1
    // issues before consuming step st; mask-fma handles <=3 straggler slots.
    int sb = srcs[beg + min(sub, dm1)];                    // step-0 sid
    v8s c = *(const v8s*)&xs[(long)sb * 64 + fo * 8];      // step-0 gather
    sb = srcs[beg + min(4 + sub, dm1)];                    // step-1 sid
    for (int st = 0; st < nst; ++st) {
        v8s n = *(const v8s*)&xs[(long)sb * 64 + fo * 8];  // step st+1 gather (clamped dup on last)
        sb = srcs[beg + min((st + 2) * 4 + sub, dm1)];     // step st+2 sid
        float m = (st * 4 + sub < d) ? 1.f : 0.f;
#pragma unroll
        for (int q = 0; q < 8; ++q) acc[q] += m * bf2f((unsigned short)c[q]);
        c = n;
    }
#pragma unroll
    for (int q = 0; q < 8; ++q) {
        acc[q] += __shfl_xor(acc[q], 8, 32);
        acc[q] += __shfl_xor(acc[q], 16, 32);
    }
    if (sub == 0) {
        float dc = dinv_[g * Nn + node];
        v8s ow = *(const v8s*)&xs[(long)node * 64 + fo * 8];
        ushort4 o0, o1;
        o0.x = f2bf((acc[0] + bf2f((unsigned short)ow[0])) * dc);
        o0.y = f2bf((acc[1] + bf2f((unsigned short)ow[1])) * dc);
        o0.z = f2bf((acc[2] + bf2f((unsigned short)ow[2])) * dc);
        o0.w = f2bf((acc[3] + bf2f((unsigned short)ow[3])) * dc);
        o1.x = f2bf((acc[4] + bf2f((unsigned short)ow[4])) * dc);
        o1.y = f2bf((acc[5] + bf2f((unsigned short)ow[5])) * dc);
        o1.z = f2bf((acc[6] + bf2f((unsigned short)ow[6])) * dc);
        o1.w = f2bf((acc[7] + bf2f((unsigned short)ow[7])) * dc);
        *(ushort4*)&z1[(long)node * 64 + fo * 8] = o0;
        *(ushort4*)&z1[(long)node * 64 + fo * 8 + 4] = o1;
    }
}

// ---------------- agg 128-feat: rolling 4-edge steps, 1-deep gather pipeline ----------------
__global__ __launch_bounds__(256) void k_agg2(const unsigned short* __restrict__ h_, const int* __restrict__ off_,
                                              const unsigned short* __restrict__ srcs_,
                                              const float* __restrict__ dinv_, unsigned short* __restrict__ z2_) {
    int g = blockIdx.y;
    const unsigned short* h = h_ + (size_t)g * Nn * 128;
    const int* off = off_ + g * (Nn + 1);
    const unsigned short* srcs = srcs_ + (size_t)g * En;
    unsigned short* z2 = z2_ + (size_t)g * Nn * 128;
    int node = blockIdx.x * 8 + (threadIdx.x >> 5);
    int lane = threadIdx.x & 31;
    int sub = lane >> 3;   // edge slot 0..3
    int fo = lane & 7;     // feature 16-tile: feats [fo*16, fo*16+16)
    int beg = off[node], end = off[node + 1];
    int d = end - beg;
    int dm1 = max(d - 1, 0);
    int nst = (d + 3) >> 2;
    float acc[16] = {};
    int sb = srcs[beg + min(sub, dm1)];
    const unsigned short* rp = &h[(long)sb * 128 + fo * 16];
    v8s c0 = *(const v8s*)rp;
    v8s c1 = *(const v8s*)(rp + 8);
    sb = srcs[beg + min(4 + sub, dm1)];
    for (int st = 0; st < nst; ++st) {
        const unsigned short* rpn = &h[(long)sb * 128 + fo * 16];
        v8s n0 = *(const v8s*)rpn;
        v8s n1 = *(const v8s*)(rpn + 8);
        sb = srcs[beg + min((st + 2) * 4 + sub, dm1)];
        float m = (st * 4 + sub < d) ? 1.f : 0.f;
#pragma unroll
        for (int q = 0; q < 8; ++q) acc[q] += m * bf2f((unsigned short)c0[q]);
#pragma unroll
        for (int q = 0; q < 8; ++q) acc[8 + q] += m * bf2f((unsigned short)c1[q]);
        c0 = n0; c1 = n1;
    }
#pragma unroll
    for (int q = 0; q < 16; ++q) {
        acc[q] += __shfl_xor(acc[q], 8, 32);
        acc[q] += __shfl_xor(acc[q], 16, 32);
    }
    if (sub == 0) {
        float dc = dinv_[g * Nn + node];
        const unsigned short* op = &h[(long)node * 128 + fo * 16];
        unsigned short* zp = &z2[(long)node * 128 + fo * 16];
#pragma unroll
        for (int q4 = 0; q4 < 4; ++q4) {
            ushort4 ow = *(const ushort4*)(op + q4 * 4);
            ushort4 o;
            o.x = f2bf((acc[q4 * 4 + 0] + bf2f(ow.x)) * dc);
            o.y = f2bf((acc[q4 * 4 + 1] + bf2f(ow.y)) * dc);
            o.z = f2bf((acc[q4 * 4 + 2] + bf2f(ow.z)) * dc);
            o.w = f2bf((acc[q4 * 4 + 3] + bf2f(ow.w)) * dc);
            *(ushort4*)(zp + q4 * 4) = o;
        }
    }
}

// ---------------- MFMA mm, all graphs: out = relu(zin@W + b) [* dinv if SCALE] ----------------
template <int K, bool SCALE>
__global__ __launch_bounds__(256) void k_mmfma(const unsigned short* __restrict__ zin_,
                                               const float* __restrict__ W, const float* __restrict__ bias,
                                               const float* __restrict__ dinv_,
                                               unsigned short* __restrict__ outp_) {
    __shared__ __align__(16) unsigned short Wt[128 * (K + 8)];
    __shared__ __align__(16) unsigned short At[32 * (K + 8)];
    int g = blockIdx.y;
    const unsigned short* zin = zin_ + (size_t)g * Nn * K;
    const float* dinv = dinv_ + g * Nn;
    unsigned short* outp = outp_ + (size_t)g * Nn * 128;
    int t = threadIdx.x;
    int base = blockIdx.x * 32;

#pragma unroll
    for (int i = 0; i < K * 128 / 256; ++i) {
        int idx = i * 256 + t;
        int k = idx >> 7, n = idx & 127;
        Wt[n * (K + 8) + k] = f2bf(W[idx]);
    }
    {
        int r = t >> 3, cb = (t & 7) * (K / 8);
        long grow = base + r;
#pragma unroll
        for (int j = 0; j < K / 32; ++j) {
            ushort4 u = make_ushort4(0, 0, 0, 0);
            if (grow < Nn) u = *(const ushort4*)&zin[grow * K + cb + j * 4];
            *(ushort4*)&At[r * (K + 8) + cb + j * 4] = u;
        }
    }
    __syncthreads();

    int w = t >> 6, lane = t & 63;
    int wm = w & 1, wn = w >> 1;
    int m = lane & 15, q = lane >> 4;
    v4f acc[4] = {};
    const unsigned short* Ap = &At[(wm * 16 + m) * (K + 8) + q * 8];
    const unsigned short* Bp = &Wt[(wn * 64 + m) * (K + 8) + q * 8];
    const int rstep = 16 * (K + 8);
#pragma unroll
    for (int ks = 0; ks < K / 32; ++ks) {
        v8s a = *(const v8s*)(Ap + ks * 32);
        v8s b0 = *(const v8s*)(Bp + 0 * rstep + ks * 32);
        v8s b1 = *(const v8s*)(Bp + 1 * rstep + ks * 32);
        v8s b2 = *(const v8s*)(Bp + 2 * rstep + ks * 32);
        v8s b3 = *(const v8s*)(Bp + 3 * rstep + ks * 32);
        acc[0] = __builtin_amdgcn_mfma_f32_16x16x32_bf16(a, b0, acc[0], 0, 0, 0);
        acc[1] = __builtin_amdgcn_mfma_f32_16x16x32_bf16(a, b1, acc[1], 0, 0, 0);
        acc[2] = __builtin_amdgcn_mfma_f32_16x16x32_bf16(a, b2, acc[2], 0, 0, 0);
        acc[3] = __builtin_amdgcn_mfma_f32_16x16x32_bf16(a, b3, acc[3], 0, 0, 0);
    }

    int col0 = wn * 64 + m;
    int rbase = base + wm * 16 + q * 4;
    float dv[4];
#pragma unroll
    for (int rg = 0; rg < 4; ++rg)
        dv[rg] = SCALE ? ((rbase + rg < Nn) ? dinv[rbase + rg] : 1.f) : 1.f;
#pragma unroll
    for (int nt = 0; nt < 4; ++nt) {
        float bc = bias[col0 + nt * 16];
#pragma unroll
        for (int rg = 0; rg < 4; ++rg) {
            int row = rbase + rg;
            if (row < Nn) {
                float o = fmaxf(acc[nt][rg] + bc, 0.f);
                outp[(long)row * 128 + col0 + nt * 16] = f2bf(o * dv[rg]);
            }
        }
    }
}

// ---------------- segment mean pool (batch sorted), all graphs ----------------
__global__ __launch_bounds__(128) void k_pool(const unsigned short* __restrict__ y_, const int* __restrict__ bat,
                                              float* __restrict__ emb_sum, float* __restrict__ cnt) {
    int g = blockIdx.y;
    const unsigned short* y = y_ + (size_t)g * Nn * 128;
    const int* batch = bat + (size_t)g * Nn;
    int f = threadIdx.x;
    int start = blockIdx.x * 64;
    int end = min(start + 64, Nn);
    if (start >= Nn) return;
    float acc = 0.f;
    int cacc = 0;
    int cur = batch[start];
    for (int i = start; i < end; ++i) {
        int b = batch[i];
        if (b != cur) {
            atomicAdd(&emb_sum[(g * Bq + cur) * Hn + f], acc);
            if (f == 0) atomicAdd(&cnt[g * Bq + cur], (float)cacc);
            acc = 0.f; cacc = 0; cur = b;
        }
        acc += bf2f(y[(long)i * Hn + f]);
        cacc++;
    }
    atomicAdd(&emb_sum[(g * Bq + cur) * Hn + f], acc);
    if (f == 0) atomicAdd(&cnt[g * Bq + cur], (float)cacc);
}

// ---------------- whole MHA: one block per batch element b ----------------
__global__ __launch_bounds__(128) void k_attn(const float* __restrict__ emb_sum, const float* __restrict__ cnt,
                                              const float* __restrict__ ipw, const float* __restrict__ ipb,
                                              const float* __restrict__ opw, const float* __restrict__ opb,
                                              float* __restrict__ pooled) {
    int b = blockIdx.x;
    int f = threadIdx.x;
    __shared__ float es[4][128], qs[4][128], ks[4][128], vs[4][128], sc[128], cx[4][128];
#pragma unroll
    for (int g = 0; g < 4; ++g) {
        float c = cnt[g * Bq + b];
        es[g][f] = (c > 0.f) ? emb_sum[(g * Bq + b) * Hn + f] / c : 0.f;
    }
    __syncthreads();
#pragma unroll
    for (int g = 0; g < 4; ++g) {
        float q = ipb[f], k = ipb[Hn + f], v = ipb[2 * Hn + f];
        for (int j = 0; j < Hn; ++j) {
            float e = es[g][j];
            q += e * ipw[f * Hn + j];
            k += e * ipw[(Hn + f) * Hn + j];
            v += e * ipw[(2 * Hn + f) * Hn + j];
        }
        qs[g][f] = q; ks[g][f] = k; vs[g][f] = v;
    }
    __syncthreads();
    {
        int h = f >> 4, g = (f >> 2) & 3, kk = f & 3;
        float s = 0.f;
        for (int d = 0; d < 16; ++d) s += qs[g][h * 16 + d] * ks[kk][h * 16 + d];
        sc[f] = s * 0.25f;
    }
    __syncthreads();
    {
        int h = f >> 4;
#pragma unroll
        for (int g = 0; g < 4; ++g) {
            int bi = h * 16 + g * 4;
            float s0 = sc[bi], s1 = sc[bi + 1], s2 = sc[bi + 2], s3 = sc[bi + 3];
            float m = fmaxf(fmaxf(s0, s1), fmaxf(s2, s3));
            float e0 = __expf(s0 - m), e1 = __expf(s1 - m), e2 = __expf(s2 - m), e3 = __expf(s3 - m);
            float rinv = 1.f / (e0 + e1 + e2 + e3);
            cx[g][f] = (e0 * vs[0][f] + e1 * vs[1][f] + e2 * vs[2][f] + e3 * vs[3][f]) * rinv;
        }
    }
    __syncthreads();
#pragma unroll
    for (int g = 0; g < 4; ++g) {
        float a = opb[f];
        for (int j = 0; j < Hn; ++j) a += cx[g][j] * opw[f * Hn + j];
        atomicAdd(&pooled[g * Hn + f], a * (1.0f / Bq));
    }
}

// ---------------- final: out[g,n] = (pooled[g] . lin_w[n] + lin_b[n]) * 60 + 50 ----------------
__global__ __launch_bounds__(256) void k_final(const float* __restrict__ pooled, const float* __restrict__ lw,
                                               const float* __restrict__ lb, float* __restrict__ out) {
    __shared__ float ps[512];
    int t = threadIdx.x;
    ps[t] = pooled[t];
    ps[t + 256] = pooled[t + 256];
    __syncthreads();
    int wave = t >> 6, lane = t & 63;
    int n = blockIdx.x * 4 + wave;
    if (n >= NNODES) return;
    float2 w = *(const float2*)&lw[(long)n * 128 + lane * 2];
    float a0 = w.x * ps[0 * 128 + lane * 2] + w.y * ps[0 * 128 + lane * 2 + 1];
    float a1 = w.x * ps[1 * 128 + lane * 2] + w.y * ps[1 * 128 + lane * 2 + 1];
    float a2 = w.x * ps[2 * 128 + lane * 2] + w.y * ps[2 * 128 + lane * 2 + 1];
    float a3 = w.x * ps[3 * 128 + lane * 2] + w.y * ps[3 * 128 + lane * 2 + 1];
#pragma unroll
    for (int off = 32; off > 0; off >>= 1) {
        a0 += __shfl_down(a0, off);
        a1 += __shfl_down(a1, off);
        a2 += __shfl_down(a2, off);
        a3 += __shfl_down(a3, off);
    }
    if (lane == 0) {
        float bn = lb[n];
        out[0 * NNODES + n] = (a0 + bn) * 60.f + 50.f;
        out[1 * NNODES + n] = (a1 + bn) * 60.f + 50.f;
        out[2 * NNODES + n] = (a2 + bn) * 60.f + 50.f;
        out[3 * NNODES + n] = (a3 + bn) * 60.f + 50.f;
    }
}

extern "C" void kernel_launch(void* const* d_in, const int* in_sizes, int n_in,
                              void* d_out, int out_size, void* d_ws, size_t ws_size,
                              hipStream_t stream) {
    const float* x   = (const float*)d_in[0];
    const int*   ei  = (const int*)d_in[1];
    const int*   bat = (const int*)d_in[2];
    const float* W1  = (const float*)d_in[3];
    const float* b1  = (const float*)d_in[4];
    const float* W2  = (const float*)d_in[5];
    const float* b2  = (const float*)d_in[6];
    const float* ipw = (const float*)d_in[7];
    const float* ipb = (const float*)d_in[8];
    const float* opw = (const float*)d_in[9];
    const float* opb = (const float*)d_in[10];
    const float* lw  = (const float*)d_in[11];
    const float* lb  = (const float*)d_in[12];
    float* out = (float*)d_out;

    // workspace carve-up (~214 MB)
    char* p = (char*)d_ws;
    unsigned short* xbs = (unsigned short*)p;                 // [4][N,64]  bf16  25.6 MB
    unsigned short* z1  = (unsigned short*)(p + 25600000);    // [4][N,64]  bf16  25.6 MB
    unsigned short* y1b = (unsigned short*)(p + 51200000);    // [4][N,128] bf16  51.2 MB
    unsigned short* z2  = (unsigned short*)(p + 102400000);   // [4][N,128] bf16  51.2 MB
    unsigned int*   pairs = (unsigned int*)(p + 102400000);   // [4][E] uint 12.8 MB (alias z2; dead before agg2)
    int* chist = (int*)(p + 102400000 + (size_t)4 * En * 4);  // [4][EB][NBK] int 307 KB (alias z2 tail; dead before agg2)
    unsigned short* y2b = (unsigned short*)(p + 153600000);   // [4][N,128] bf16  51.2 MB
    char* meta = p + 204800000;
    int*   off  = (int*)meta;                                 // [4][N+1]
    float* dinv = (float*)(off + 4 * (Nn + 1));               // [4][N]
    int*   btot  = (int*)(dinv + 4 * Nn);                     // [4][NBK]
    int*   bbase = btot + 4 * NBK;                            // [4][NBK]
    int*   bcur  = bbase + 4 * NBK;                           // [4][NBK]
    unsigned short* srcs = (unsigned short*)(bcur + 4 * NBK); // [4][E] ushort 6.4 MB
    float* emb    = (float*)(srcs + (size_t)4 * En);          // [G,B,H]
    float* cnt    = emb + Gn * Bq * Hn;                       // [G,B]
    float* pooled = cnt + Gn * Bq;                            // [G,H]

    hipMemsetAsync(btot, 0, 4 * NBK * sizeof(int), stream);
    hipMemsetAsync(emb, 0, Gn * Bq * Hn * sizeof(float), stream);
    hipMemsetAsync(cnt, 0, Gn * Bq * sizeof(float), stream);
    hipMemsetAsync(pooled, 0, Gn * Hn * sizeof(float), stream);

    const int agGrid = (Nn + 7) / 8;                 // 6250
    const int mmGrid = (Nn + 31) / 32;               // 1563
    const int plGrid = (Nn + 63) / 64;               // 782
    const int ctGrid = (Nn * 16 + 255) / 256;        // 3125

    // CSR build: totals+chunk hists -> bases -> bucketize (hist reuse) -> fused fill
    k_btot<<<dim3(EB, Gn), 256, 0, stream>>>(ei, btot, chist);
    k_bbase<<<Gn, 256, 0, stream>>>(btot, bbase, bcur);
    k_bucket<<<dim3(EB, Gn), 256, 0, stream>>>(ei, bcur, pairs, chist);
    k_fillb2<<<dim3(NBK, Gn), 256, 0, stream>>>(pairs, bbase, btot, off, dinv, srcs);

    // GCN layers, all graphs per launch
    k_cast<<<dim3(ctGrid, Gn), 256, 0, stream>>>(x, dinv, xbs);
    k_agg1<<<dim3(agGrid, Gn), 256, 0, stream>>>(xbs, off, srcs, dinv, z1);
    k_mmfma<64, true><<<dim3(mmGrid, Gn), 256, 0, stream>>>(z1, W1, b1, dinv, y1b);
    k_agg2<<<dim3(agGrid, Gn), 256, 0, stream>>>(y1b, off, srcs, dinv, z2);
    k_mmfma<128, false><<<dim3(mmGrid, Gn), 256, 0, stream>>>(z2, W2, b2, dinv, y2b);
    k_pool<<<dim3(plGrid, Gn), 128, 0, stream>>>(y2b, bat, emb, cnt);

    k_attn<<<Bq, 128, 0, stream>>>(emb, cnt, ipw, ipb, opw, opb, pooled);
    k_final<<<(NNODES + 3) / 4, 256, 0, stream>>>(pooled, lw, lb, out);
}